// Round 10
// baseline (153.992 us; speedup 1.0000x reference)
//
#include <hip/hip_runtime.h>

#define BATCH 4
#define SEQ 4096
#define DMODEL 1024
#define HDIM 64

#define QBLK 64      // q rows per wave (2 groups of 32)
#define NQT 64       // 64-row q-tiles per batch
#define CHUNK 256    // KV positions per wave
#define ITERS 8      // CHUNK / 32
#define BSLOT 544    // per-batch valid (qt,chunk) slots = sum_qt (qt/4 + 1)

typedef _Float16 h16;
typedef _Float16 h16x8 __attribute__((ext_vector_type(8)));
typedef _Float16 h16x4 __attribute__((ext_vector_type(4)));
typedef float f32x4 __attribute__((ext_vector_type(4)));
typedef float f32x16 __attribute__((ext_vector_type(16)));

#define WT_ELEMS (192 * DMODEL)
#define QK_ELEMS (BATCH * SEQ * HDIM)       // 1048576
#define NSLOT (BATCH * BSLOT)

// valid-slot prefix: qt = 4a+b -> sum_{q<qt} (q/4+1) = (a+1)(2a+b)
__device__ __forceinline__ int slot_base(int qt) {
    int a = qt >> 2, b = qt & 3;
    return (a + 1) * (2 * a + b);
}

// k-slot permutation for MFMA A/B fragments: swap bits 2<->3 (self-inverse)
__device__ __forceinline__ int kperm(int u) {
    return (u & 3) | (((u >> 2) & 1) << 3) | (((u >> 3) & 1) << 2);
}

// compiler-proof async loads; completion via explicit counted vmcnt
__device__ __forceinline__ void gload(h16x8& dst, const h16* p) {
    asm volatile("global_load_dwordx4 %0, %1, off" : "=v"(dst) : "v"(p));
}
template<int OFF>
__device__ __forceinline__ void gloadf_o(f32x4& dst, const float* p) {
    asm volatile("global_load_dwordx4 %0, %1, off offset:%2" : "=v"(dst) : "v"(p), "n"(OFF));
}
template<int OFF>
__device__ __forceinline__ void gloadw_o(h16x8& dst, const h16* p) {
    asm volatile("global_load_dwordx4 %0, %1, off offset:%2" : "=v"(dst) : "v"(p), "n"(OFF));
}

// ---------------- prep: Wt transpose + fp16 convert ----------------
__global__ __launch_bounds__(256) void prep(const float* __restrict__ Wq,
                                            const float* __restrict__ Wk,
                                            const float* __restrict__ Wv,
                                            h16* __restrict__ Wt) {
    int b = blockIdx.x;  // 0..191
    const float* W = (b < 64) ? Wq : (b < 128) ? Wk : Wv;
    int c = b & 63;
    for (int k = threadIdx.x; k < DMODEL; k += 256)
        Wt[b * DMODEL + k] = (h16)W[k * HDIM + c];
}

// ---------------- QKV projection GEMM: M=16384, K=1024, N=192, asm-pipelined ----------------
// grid 512 (32-row tiles); 4 waves: wave w -> 48 N-cols. 2 M-frags x 3 N-frags.
// Quad-buffered (sets A-D) offset-folded global_load_dwordx4; vmcnt(21) steady state.
// Q pre-scaled by 1/8; V stored transposed [B][H][T] with kperm within 16-groups.

#define QISSUE(S, T)                                                          \
    gloadf_o<(T)*128>(a##S##0, xp0);                                          \
    gloadf_o<(T)*128+16>(a##S##1, xp0);                                       \
    gloadf_o<(T)*128>(a##S##2, xp1);                                          \
    gloadf_o<(T)*128+16>(a##S##3, xp1);                                       \
    gloadw_o<(T)*64>(b##S##0, wt0);                                           \
    gloadw_o<(T)*64>(b##S##1, wt1);                                           \
    gloadw_o<(T)*64>(b##S##2, wt2);

#define QCOMPUTE(S) {                                                         \
    h16x8 av0, av1;                                                           \
    for (int j = 0; j < 4; j++) {                                             \
        av0[j] = (h16)a##S##0[j]; av0[j + 4] = (h16)a##S##1[j];               \
        av1[j] = (h16)a##S##2[j]; av1[j + 4] = (h16)a##S##3[j];               \
    }                                                                         \
    c00 = __builtin_amdgcn_mfma_f32_16x16x32_f16(av0, b##S##0, c00, 0, 0, 0); \
    c01 = __builtin_amdgcn_mfma_f32_16x16x32_f16(av0, b##S##1, c01, 0, 0, 0); \
    c02 = __builtin_amdgcn_mfma_f32_16x16x32_f16(av0, b##S##2, c02, 0, 0, 0); \
    c10 = __builtin_amdgcn_mfma_f32_16x16x32_f16(av1, b##S##0, c10, 0, 0, 0); \
    c11 = __builtin_amdgcn_mfma_f32_16x16x32_f16(av1, b##S##1, c11, 0, 0, 0); \
    c12 = __builtin_amdgcn_mfma_f32_16x16x32_f16(av1, b##S##2, c12, 0, 0, 0); }

#define QS(S, T, N) {                                                         \
    asm volatile("s_waitcnt vmcnt(" #N ")" ::: "memory");                     \
    __builtin_amdgcn_sched_barrier(0);                                        \
    QCOMPUTE(S)                                                               \
    if ((T) + 4 < 32) { QISSUE(S, (T) + 4) } }

__global__ __launch_bounds__(256, 2) void qkv_proj(
    const float* __restrict__ x, const h16* __restrict__ Wt,
    const float* __restrict__ bq, const float* __restrict__ bk, const float* __restrict__ bv,
    h16* __restrict__ Q, h16* __restrict__ K, h16* __restrict__ Vt)
{
    int lane = threadIdx.x & 63;
    int w = threadIdx.x >> 6;
    int r0 = blockIdx.x * 32;
    int ln15 = lane & 15;
    int kc = (lane >> 4) * 8;

    const float* xp0 = x + (size_t)(r0 + ln15) * DMODEL + kc;
    const float* xp1 = xp0 + 16 * DMODEL;
    const h16* wt0 = Wt + (size_t)(48 * w + ln15) * DMODEL + kc;
    const h16* wt1 = wt0 + 16 * DMODEL;
    const h16* wt2 = wt0 + 32 * DMODEL;

    f32x4 aA0, aA1, aA2, aA3, aB0, aB1, aB2, aB3;
    f32x4 aC0, aC1, aC2, aC3, aD0, aD1, aD2, aD3;
    h16x8 bA0, bA1, bA2, bB0, bB1, bB2, bC0, bC1, bC2, bD0, bD1, bD2;
    f32x4 c00 = {}, c01 = {}, c02 = {}, c10 = {}, c11 = {}, c12 = {};

    QISSUE(A, 0) QISSUE(B, 1) QISSUE(C, 2) QISSUE(D, 3)   // 28 loads in flight

    QS(A, 0, 21)  QS(B, 1, 21)  QS(C, 2, 21)  QS(D, 3, 21)
    QS(A, 4, 21)  QS(B, 5, 21)  QS(C, 6, 21)  QS(D, 7, 21)
    QS(A, 8, 21)  QS(B, 9, 21)  QS(C, 10, 21) QS(D, 11, 21)
    QS(A, 12, 21) QS(B, 13, 21) QS(C, 14, 21) QS(D, 15, 21)
    QS(A, 16, 21) QS(B, 17, 21) QS(C, 18, 21) QS(D, 19, 21)
    QS(A, 20, 21) QS(B, 21, 21) QS(C, 22, 21) QS(D, 23, 21)
    QS(A, 24, 21) QS(B, 25, 21) QS(C, 26, 21) QS(D, 27, 21)
    QS(A, 28, 21) QS(B, 29, 14) QS(C, 30, 7)  QS(D, 31, 0)

    f32x4 acc[2][3] = {{c00, c01, c02}, {c10, c11, c12}};
    #pragma unroll
    for (int f = 0; f < 3; f++) {
        int col = 48 * w + 16 * f + ln15;
        float bias = (col < 64) ? bq[col] : (col < 128) ? bk[col - 64] : bv[col - 128];
        #pragma unroll
        for (int m = 0; m < 2; m++) {
            #pragma unroll
            for (int i = 0; i < 4; i++) {
                int t = r0 + 16 * m + (lane >> 4) * 4 + i;
                int bb = t >> 12;
                int tt = t & (SEQ - 1);
                float v = acc[m][f][i] + bias;
                if (col < 64)
                    Q[((size_t)bb * SEQ + tt) * HDIM + col] = (h16)(v * 0.125f);
                else if (col < 128)
                    K[((size_t)bb * SEQ + tt) * HDIM + (col - 64)] = (h16)v;
                else {
                    int tp = (tt & ~15) | kperm(tt & 15);
                    Vt[((size_t)bb * HDIM + (col - 128)) * SEQ + tp] = (h16)v;
                }
            }
        }
    }
}

// ---------------- flash compute step (one 32-row q-group): QK -> softmax -> PV ----------------
__device__ __forceinline__ void flash_compute(
    h16x8 K0, h16x8 K1, h16x8 K2, h16x8 K3,
    h16x8 V0, h16x8 V1, h16x8 V2, h16x8 V3,
    h16x8 q0v, h16x8 q1v, h16x8 q2v, h16x8 q3v,
    int kt0, int q0g, int qg, int hi,
    f32x16& o0, f32x16& o1, float& m_i, float& l_i)
{
    f32x16 s = {};
    __builtin_amdgcn_s_setprio(1);
    s = __builtin_amdgcn_mfma_f32_32x32x16_f16(K0, q0v, s, 0, 0, 0);
    s = __builtin_amdgcn_mfma_f32_32x32x16_f16(K1, q1v, s, 0, 0, 0);
    s = __builtin_amdgcn_mfma_f32_32x32x16_f16(K2, q2v, s, 0, 0, 0);
    s = __builtin_amdgcn_mfma_f32_32x32x16_f16(K3, q3v, s, 0, 0, 0);
    __builtin_amdgcn_s_setprio(0);

    float sc[16];
    #pragma unroll
    for (int r = 0; r < 16; r++) sc[r] = s[r];
    if (kt0 + 31 > q0g) {  // tile may contain masked entries for this group (uniform test)
        #pragma unroll
        for (int r = 0; r < 16; r++) {
            int kg = kt0 + (r & 3) + 8 * (r >> 2) + 4 * hi;
            if (kg > qg) sc[r] = -1e30f;
        }
    }
    float tm = sc[0];
    #pragma unroll
    for (int r = 1; r < 16; r++) tm = fmaxf(tm, sc[r]);
    tm = fmaxf(tm, __shfl_xor(tm, 32));
    float mn = fmaxf(m_i, tm);
    float al = __expf(m_i - mn);
    m_i = mn;
    float p[16], rs = 0.f;
    #pragma unroll
    for (int r = 0; r < 16; r++) { p[r] = __expf(sc[r] - mn); rs += p[r]; }
    rs += __shfl_xor(rs, 32);
    l_i = l_i * al + rs;
    #pragma unroll
    for (int r = 0; r < 16; r++) { o0[r] *= al; o1[r] *= al; }

    h16x8 pb0, pb1;
    #pragma unroll
    for (int j = 0; j < 8; j++) { pb0[j] = (h16)p[j]; pb1[j] = (h16)p[8 + j]; }

    __builtin_amdgcn_s_setprio(1);
    o0 = __builtin_amdgcn_mfma_f32_32x32x16_f16(V0, pb0, o0, 0, 0, 0);
    o0 = __builtin_amdgcn_mfma_f32_32x32x16_f16(V1, pb1, o0, 0, 0, 0);
    o1 = __builtin_amdgcn_mfma_f32_32x32x16_f16(V2, pb0, o1, 0, 0, 0);
    o1 = __builtin_amdgcn_mfma_f32_32x32x16_f16(V3, pb1, o1, 0, 0, 0);
    __builtin_amdgcn_s_setprio(0);
}

// issue the 8 loads for one 32-wide KV tile into named buffer set B (A or B)
#define ISSUE(B, KT) {                                                        \
    const h16* kp_ = krow + (size_t)(KT) * HDIM;                              \
    gload(k##B##0, kp_);      gload(k##B##1, kp_ + 16);                       \
    gload(k##B##2, kp_ + 32); gload(k##B##3, kp_ + 48);                       \
    gload(v##B##0, vrow0 + (KT));      gload(v##B##1, vrow0 + (KT) + 16);     \
    gload(v##B##2, vrow1 + (KT));      gload(v##B##3, vrow1 + (KT) + 16); }

// both q-groups consume the same K/V tile
#define COMPUTE(B, T) {                                                       \
    flash_compute(k##B##0, k##B##1, k##B##2, k##B##3,                         \
                  v##B##0, v##B##1, v##B##2, v##B##3,                         \
                  qa0, qa1, qa2, qa3, S + 32 * (T), q0, qg0, hi,              \
                  o00, o01, m0, l0);                                          \
    flash_compute(k##B##0, k##B##1, k##B##2, k##B##3,                         \
                  v##B##0, v##B##1, v##B##2, v##B##3,                         \
                  qc0, qc1, qc2, qc3, S + 32 * (T), q0 + 32, qg1, hi,         \
                  o10, o11, m1, l1); }

#define STEP(CUR, NXT, T) {                                                   \
    ISSUE(NXT, S + 32 * ((T) + 1))                                            \
    asm volatile("s_waitcnt vmcnt(8)" ::: "memory");                          \
    __builtin_amdgcn_sched_barrier(0);                                        \
    COMPUTE(CUR, T) }

#define STEP_LAST(CUR, T) {                                                   \
    asm volatile("s_waitcnt vmcnt(0)" ::: "memory");                          \
    __builtin_amdgcn_sched_barrier(0);                                        \
    COMPUTE(CUR, T) }

// ---------------- causal flash attention partial: 64 q-rows/wave, asm-pipelined ----------------
__global__ __launch_bounds__(256, 2) void flash(
    const h16* __restrict__ Q, const h16* __restrict__ K, const h16* __restrict__ Vt,
    h16* __restrict__ o_part, float* __restrict__ ml_part)
{
    int wid = threadIdx.x >> 6;
    int lane = threadIdx.x & 63;
    int bid = blockIdx.x;                  // grid = BATCH*NQT*5
    int quarter = bid % 5;
    int rest = bid / 5;
    int qtflip = rest & (NQT - 1);
    int batch = rest >> 6;
    int qt = NQT - 1 - qtflip;             // longest q-tiles first
    int c = quarter * 4 + wid;
    int nc = (qt >> 2) + 1;
    if (c >= nc) return;

    int q0 = qt * QBLK;
    int S = c * CHUNK;
    int l31 = lane & 31;
    int hi = lane >> 5;
    int qg0 = q0 + l31;
    int qg1 = q0 + 32 + l31;

    const h16* Qb = Q + (size_t)batch * SEQ * HDIM;
    const h16* Kb = K + (size_t)batch * SEQ * HDIM;
    const h16* Vb = Vt + (size_t)batch * HDIM * SEQ;
    const h16* krow = Kb + (size_t)l31 * HDIM + 8 * hi;
    const h16* vrow0 = Vb + (size_t)l31 * SEQ + 8 * hi;
    const h16* vrow1 = Vb + (size_t)(32 + l31) * SEQ + 8 * hi;

    // Q fragments for both groups (asm loads; drained by first STEP's vmcnt(8))
    h16x8 qa0, qa1, qa2, qa3, qc0, qc1, qc2, qc3;
    {
        const h16* qp = Qb + (size_t)(q0 + l31) * HDIM + 8 * hi;
        gload(qa0, qp); gload(qa1, qp + 16); gload(qa2, qp + 32); gload(qa3, qp + 48);
        const h16* qp2 = qp + 32 * HDIM;
        gload(qc0, qp2); gload(qc1, qp2 + 16); gload(qc2, qp2 + 32); gload(qc3, qp2 + 48);
    }

    h16x8 kA0, kA1, kA2, kA3, vA0, vA1, vA2, vA3;
    h16x8 kB0, kB1, kB2, kB3, vB0, vB1, vB2, vB3;

    f32x16 o00 = {}, o01 = {}, o10 = {}, o11 = {};
    float m0 = -1e30f, l0 = 0.f, m1 = -1e30f, l1 = 0.f;

    ISSUE(A, S)            // prologue: 8 qb + 8 tile0 in flight

    STEP(A, B, 0)          // issue tile1 -> 24 out; vmcnt(8) = qb+tile0 done
    STEP(B, A, 1)
    STEP(A, B, 2)
    STEP(B, A, 3)
    STEP(A, B, 4)
    STEP(B, A, 5)
    STEP(A, B, 6)
    STEP_LAST(B, 7)

    // write l-normalized partials (f16) + (m, l) f32 for both groups
    size_t slot = (size_t)batch * BSLOT + slot_base(qt) + c;
    h16* opb = o_part + slot * (QBLK * 64);
    {
        float inv = 1.f / l0;
        h16* op = opb + l31 * 64;
        #pragma unroll
        for (int q = 0; q < 4; q++) {
            h16x4 pk0, pk1;
            #pragma unroll
            for (int i = 0; i < 4; i++) {
                pk0[i] = (h16)(o00[4 * q + i] * inv);
                pk1[i] = (h16)(o01[4 * q + i] * inv);
            }
            *(h16x4*)(op + 8 * q + 4 * hi) = pk0;
            *(h16x4*)(op + 32 + 8 * q + 4 * hi) = pk1;
        }
    }
    {
        float inv = 1.f / l1;
        h16* op = opb + (32 + l31) * 64;
        #pragma unroll
        for (int q = 0; q < 4; q++) {
            h16x4 pk0, pk1;
            #pragma unroll
            for (int i = 0; i < 4; i++) {
                pk0[i] = (h16)(o10[4 * q + i] * inv);
                pk1[i] = (h16)(o11[4 * q + i] * inv);
            }
            *(h16x4*)(op + 8 * q + 4 * hi) = pk0;
            *(h16x4*)(op + 32 + 8 * q + 4 * hi) = pk1;
        }
    }
    if (hi == 0) {
        ml_part[slot * 128 + l31 * 2] = m0;
        ml_part[slot * 128 + l31 * 2 + 1] = l0;
        ml_part[slot * 128 + (32 + l31) * 2] = m1;
        ml_part[slot * 128 + (32 + l31) * 2 + 1] = l1;
    }
}

// ---------------- combine partials: one block per (batch, qt, row-half of 32) ----------------
__global__ __launch_bounds__(256) void combine(
    const h16* __restrict__ o_part, const float* __restrict__ ml_part,
    float* __restrict__ out)
{
    int bid = blockIdx.x;           // BATCH*NQT*2
    int rh = bid & 1;
    int tile = bid >> 1;
    int batch = tile >> 6;
    int qt = tile & (NQT - 1);
    int q0 = qt * QBLK;
    int nc = (qt >> 2) + 1;
    int col = threadIdx.x & 63;
    int rg = threadIdx.x >> 6;      // 0..3
    size_t base = (size_t)batch * BSLOT + slot_base(qt);

    #pragma unroll
    for (int j = 0; j < 8; j++) {
        int r = rh * 32 + rg * 8 + j;
        float M = -1e30f;
        for (int c = 0; c < nc; c++)
            M = fmaxf(M, ml_part[(base + c) * 128 + r * 2]);
        float L = 0.f, acc = 0.f;
        for (int c = 0; c < nc; c++) {
            float mc = ml_part[(base + c) * 128 + r * 2];
            float lc = ml_part[(base + c) * 128 + r * 2 + 1];
            float wgt = __expf(mc - M) * lc;
            L += wgt;
            acc += wgt * (float)o_part[(base + c) * (QBLK * 64) + r * 64 + col];
        }
        out[((size_t)batch * SEQ + q0 + r) * HDIM + col] = acc / L;
    }
}

extern "C" void kernel_launch(void* const* d_in, const int* in_sizes, int n_in,
                              void* d_out, int out_size, void* d_ws, size_t ws_size,
                              hipStream_t stream) {
    const float* x  = (const float*)d_in[0];
    const float* Wq = (const float*)d_in[1];
    const float* bq = (const float*)d_in[2];
    const float* Wk = (const float*)d_in[3];
    const float* bk = (const float*)d_in[4];
    const float* Wv = (const float*)d_in[5];
    const float* bv = (const float*)d_in[6];
    float* out = (float*)d_out;

    h16* Wt = (h16*)d_ws;
    h16* Q  = Wt + WT_ELEMS;
    h16* K  = Q + QK_ELEMS;
    h16* Vt = K + QK_ELEMS;
    h16* o_part = Vt + QK_ELEMS;
    float* ml_part = (float*)(o_part + (size_t)NSLOT * QBLK * 64);
    // peak ws use ~= 25.3 MiB

    hipLaunchKernelGGL(prep, dim3(192), dim3(256), 0, stream, Wq, Wk, Wv, Wt);
    hipLaunchKernelGGL(qkv_proj, dim3(512), dim3(256), 0, stream,
                       x, Wt, bq, bk, bv, Q, K, Vt);
    hipLaunchKernelGGL(flash, dim3(BATCH * NQT * 5), dim3(256), 0, stream,
                       Q, K, Vt, o_part, ml_part);
    hipLaunchKernelGGL(combine, dim3(BATCH * NQT * 2), dim3(256), 0, stream,
                       o_part, ml_part, out);
}

// Round 11
// 117.543 us; speedup vs baseline: 1.3101x; 1.3101x over previous
//
#include <hip/hip_runtime.h>

#define BATCH 4
#define SEQ 4096
#define DMODEL 1024
#define HDIM 64

#define QBLK 64      // q rows per wave (2 groups of 32)
#define NQT 64       // 64-row q-tiles per batch
#define CHUNK 256    // KV positions per wave
#define ITERS 8      // CHUNK / 32
#define BSLOT 544    // per-batch valid (qt,chunk) slots = sum_qt (qt/4 + 1)

typedef _Float16 h16;
typedef _Float16 h16x8 __attribute__((ext_vector_type(8)));
typedef _Float16 h16x4 __attribute__((ext_vector_type(4)));
typedef float f32x4 __attribute__((ext_vector_type(4)));
typedef float f32x16 __attribute__((ext_vector_type(16)));

#define WF_ELEMS (12 * 32 * 64 * 8)         // 196608 h16, frag-packed W
#define QK_ELEMS (BATCH * SEQ * HDIM)       // 1048576 h16 each for Q/K/V frag
#define PB 262144                            // per-batch h16 in Q/K/V frag (128 tiles * 2048)
#define NSLOT (BATCH * BSLOT)

// valid-slot prefix: qt = 4a+b -> sum_{q<qt} (q/4+1) = (a+1)(2a+b)
__device__ __forceinline__ int slot_base(int qt) {
    int a = qt >> 2, b = qt & 3;
    return (a + 1) * (2 * a + b);
}

// k-slot permutation for MFMA A/B fragments: swap bits 2<->3 (self-inverse)
__device__ __forceinline__ int kperm(int u) {
    return (u & 3) | (((u >> 2) & 1) << 3) | (((u >> 3) & 1) << 2);
}

// compiler-proof async loads; completion via explicit counted vmcnt
template<int OFF>
__device__ __forceinline__ void gload_o(h16x8& dst, const h16* p) {
    asm volatile("global_load_dwordx4 %0, %1, off offset:%2" : "=v"(dst) : "v"(p), "n"(OFF));
}

// ---------------- prep: frag-pack W (f32->f16) and x (f32->f16) ----------------
// W_frag[fg(12)][kt(32)][lane][8]: lane=(kgrp*16+ln15) holds W[32kt+8kgrp+e][16fg+ln15]
// xh_frag[mt(1024)][kt(32)][lane][8]: lane holds x[16mt+ln15][32kt+8kgrp+e]
__global__ __launch_bounds__(256) void prep(const float* __restrict__ Wq,
                                            const float* __restrict__ Wk,
                                            const float* __restrict__ Wv,
                                            const float* __restrict__ x,
                                            h16* __restrict__ Wf,
                                            h16* __restrict__ xh) {
    int b = blockIdx.x;
    if (b < 96) {
        int flat = b * 256 + threadIdx.x;     // (fg, kt, lane)
        int lane = flat & 63;
        int kt = (flat >> 6) & 31;
        int fg = flat >> 11;                  // 0..11
        int col = 16 * fg + (lane & 15);
        const float* W = (col < 64) ? Wq : (col < 128) ? Wk : Wv;
        int c = col & 63;
        int k0 = 32 * kt + 8 * (lane >> 4);
        h16x8 v;
        #pragma unroll
        for (int j = 0; j < 8; j++) v[j] = (h16)W[(size_t)(k0 + j) * 64 + c];
        *(h16x8*)(Wf + (size_t)flat * 8) = v;
        return;
    }
    size_t flat = (size_t)(b - 96) * 256 + threadIdx.x;   // (mt, kt, lane)
    int lane = (int)(flat & 63);
    int kt = (int)((flat >> 6) & 31);
    int mt = (int)(flat >> 11);               // 0..1023
    const float* xp = x + (size_t)(16 * mt + (lane & 15)) * DMODEL + 32 * kt + 8 * (lane >> 4);
    f32x4 lo = *(const f32x4*)xp;
    f32x4 hi = *(const f32x4*)(xp + 4);
    h16x8 v;
    #pragma unroll
    for (int j = 0; j < 4; j++) { v[j] = (h16)lo[j]; v[j + 4] = (h16)hi[j]; }
    *(h16x8*)(xh + flat * 8) = v;
}

// ---------------- QKV projection GEMM: frag-packed coalesced loads, quad-buffered ----------------
#define QISSUE(S, IMM)                                                        \
    gload_o<IMM>(a##S##0, ax0); gload_o<IMM>(a##S##1, ax1);                   \
    gload_o<IMM>(b##S##0, w0);  gload_o<IMM>(b##S##1, w1);                    \
    gload_o<IMM>(b##S##2, w2);

#define QCOMPUTE(S)                                                           \
    c00 = __builtin_amdgcn_mfma_f32_16x16x32_f16(a##S##0, b##S##0, c00, 0, 0, 0); \
    c01 = __builtin_amdgcn_mfma_f32_16x16x32_f16(a##S##0, b##S##1, c01, 0, 0, 0); \
    c02 = __builtin_amdgcn_mfma_f32_16x16x32_f16(a##S##0, b##S##2, c02, 0, 0, 0); \
    c10 = __builtin_amdgcn_mfma_f32_16x16x32_f16(a##S##1, b##S##0, c10, 0, 0, 0); \
    c11 = __builtin_amdgcn_mfma_f32_16x16x32_f16(a##S##1, b##S##1, c11, 0, 0, 0); \
    c12 = __builtin_amdgcn_mfma_f32_16x16x32_f16(a##S##1, b##S##2, c12, 0, 0, 0);

#define QSTEP(S, N) {                                                         \
    asm volatile("s_waitcnt vmcnt(" #N ")" ::: "memory");                     \
    __builtin_amdgcn_sched_barrier(0);                                        \
    QCOMPUTE(S)                                                               \
    QISSUE(S, 3072)                                                           \
    ax0 += 512; ax1 += 512; w0 += 512; w1 += 512; w2 += 512; }

#define QSTEP_T(S, N) {                                                       \
    asm volatile("s_waitcnt vmcnt(" #N ")" ::: "memory");                     \
    __builtin_amdgcn_sched_barrier(0);                                        \
    QCOMPUTE(S) }

__global__ __launch_bounds__(256, 2) void qkv_proj(
    const h16* __restrict__ xh, const h16* __restrict__ Wf,
    const float* __restrict__ bq, const float* __restrict__ bk, const float* __restrict__ bv,
    h16* __restrict__ Qf, h16* __restrict__ Kf, h16* __restrict__ Vf)
{
    int lane = threadIdx.x & 63;
    int w = threadIdx.x >> 6;
    int r0 = blockIdx.x * 32;
    int ln15 = lane & 15;

    // base pointers start at kt=1 (prologue offsets -1024..2048, steady +3072)
    const h16* ax0 = xh + (size_t)(2 * blockIdx.x) * 16384 + lane * 8 + 512;
    const h16* ax1 = ax0 + 16384;
    const h16* w0 = Wf + (size_t)(3 * w) * 16384 + lane * 8 + 512;
    const h16* w1 = w0 + 16384;
    const h16* w2 = w0 + 32768;

    h16x8 aA0, aA1, bA0, bA1, bA2;
    h16x8 aB0, aB1, bB0, bB1, bB2;
    h16x8 aC0, aC1, bC0, bC1, bC2;
    h16x8 aD0, aD1, bD0, bD1, bD2;
    f32x4 c00 = {}, c01 = {}, c02 = {}, c10 = {}, c11 = {}, c12 = {};

    QISSUE(A, -1024) QISSUE(B, 0) QISSUE(C, 1024) QISSUE(D, 2048)   // 20 in flight

    QSTEP(A, 15) QSTEP(B, 15) QSTEP(C, 15) QSTEP(D, 15)
    QSTEP(A, 15) QSTEP(B, 15) QSTEP(C, 15) QSTEP(D, 15)
    QSTEP(A, 15) QSTEP(B, 15) QSTEP(C, 15) QSTEP(D, 15)
    QSTEP(A, 15) QSTEP(B, 15) QSTEP(C, 15) QSTEP(D, 15)
    QSTEP(A, 15) QSTEP(B, 15) QSTEP(C, 15) QSTEP(D, 15)
    QSTEP(A, 15) QSTEP(B, 15) QSTEP(C, 15) QSTEP(D, 15)
    QSTEP(A, 15) QSTEP(B, 15) QSTEP(C, 15) QSTEP(D, 15)
    QSTEP_T(A, 15) QSTEP_T(B, 10) QSTEP_T(C, 5) QSTEP_T(D, 0)

    // epilogue: +bias, scatter-write into fragment-packed Q/K/V layouts
    f32x4 acc[2][3] = {{c00, c01, c02}, {c10, c11, c12}};
    #pragma unroll
    for (int f = 0; f < 3; f++) {
        int col = 48 * w + 16 * f + ln15;
        float bias = (col < 64) ? bq[col] : (col < 128) ? bk[col - 64] : bv[col - 128];
        #pragma unroll
        for (int m = 0; m < 2; m++) {
            #pragma unroll
            for (int i = 0; i < 4; i++) {
                int t = r0 + 16 * m + (lane >> 4) * 4 + i;
                int bb = t >> 12;
                int tt = t & (SEQ - 1);
                float v = acc[m][f][i] + bias;
                if (col < 64) {          // Q: frag[tq][d][hi*32+l31][e], pre-scaled
                    int d = col >> 4, hh = (col >> 3) & 1, e = col & 7;
                    Qf[(size_t)bb * PB + (tt >> 5) * 2048 + d * 512 +
                       (hh * 32 + (tt & 31)) * 8 + e] = (h16)(v * 0.125f);
                } else if (col < 128) {  // K
                    int ck = col - 64;
                    int d = ck >> 4, hh = (ck >> 3) & 1, e = ck & 7;
                    Kf[(size_t)bb * PB + (tt >> 5) * 2048 + d * 512 +
                       (hh * 32 + (tt & 31)) * 8 + e] = (h16)v;
                } else {                 // V: kperm folded into index
                    int h = col - 128;
                    int tp = (tt & ~15) | kperm(tt & 15);
                    int j = ((h >> 5) << 1) | ((tp >> 4) & 1);
                    Vf[(size_t)bb * PB + (tp >> 5) * 2048 + j * 512 +
                       (((tp >> 3) & 1) * 32 + (h & 31)) * 8 + (tp & 7)] = (h16)v;
                }
            }
        }
    }
}

// ---------------- flash compute step (one 32-row q-group): QK -> softmax -> PV ----------------
__device__ __forceinline__ void flash_compute(
    h16x8 K0, h16x8 K1, h16x8 K2, h16x8 K3,
    h16x8 V0, h16x8 V1, h16x8 V2, h16x8 V3,
    h16x8 q0v, h16x8 q1v, h16x8 q2v, h16x8 q3v,
    int kt0, int q0g, int qg, int hi,
    f32x16& o0, f32x16& o1, float& m_i, float& l_i)
{
    f32x16 s = {};
    __builtin_amdgcn_s_setprio(1);
    s = __builtin_amdgcn_mfma_f32_32x32x16_f16(K0, q0v, s, 0, 0, 0);
    s = __builtin_amdgcn_mfma_f32_32x32x16_f16(K1, q1v, s, 0, 0, 0);
    s = __builtin_amdgcn_mfma_f32_32x32x16_f16(K2, q2v, s, 0, 0, 0);
    s = __builtin_amdgcn_mfma_f32_32x32x16_f16(K3, q3v, s, 0, 0, 0);
    __builtin_amdgcn_s_setprio(0);

    float sc[16];
    #pragma unroll
    for (int r = 0; r < 16; r++) sc[r] = s[r];
    if (kt0 + 31 > q0g) {
        #pragma unroll
        for (int r = 0; r < 16; r++) {
            int kg = kt0 + (r & 3) + 8 * (r >> 2) + 4 * hi;
            if (kg > qg) sc[r] = -1e30f;
        }
    }
    float tm = sc[0];
    #pragma unroll
    for (int r = 1; r < 16; r++) tm = fmaxf(tm, sc[r]);
    tm = fmaxf(tm, __shfl_xor(tm, 32));
    float mn = fmaxf(m_i, tm);
    float al = __expf(m_i - mn);
    m_i = mn;
    float p[16], rs = 0.f;
    #pragma unroll
    for (int r = 0; r < 16; r++) { p[r] = __expf(sc[r] - mn); rs += p[r]; }
    rs += __shfl_xor(rs, 32);
    l_i = l_i * al + rs;
    #pragma unroll
    for (int r = 0; r < 16; r++) { o0[r] *= al; o1[r] *= al; }

    h16x8 pb0, pb1;
    #pragma unroll
    for (int j = 0; j < 8; j++) { pb0[j] = (h16)p[j]; pb1[j] = (h16)p[8 + j]; }

    __builtin_amdgcn_s_setprio(1);
    o0 = __builtin_amdgcn_mfma_f32_32x32x16_f16(V0, pb0, o0, 0, 0, 0);
    o0 = __builtin_amdgcn_mfma_f32_32x32x16_f16(V1, pb1, o0, 0, 0, 0);
    o1 = __builtin_amdgcn_mfma_f32_32x32x16_f16(V2, pb0, o1, 0, 0, 0);
    o1 = __builtin_amdgcn_mfma_f32_32x32x16_f16(V3, pb1, o1, 0, 0, 0);
    __builtin_amdgcn_s_setprio(0);
}

// coalesced frag loads for one 32-kv tile (4 K + 4 V), then advance 4KB
#define ISSUE(B) {                                                            \
    gload_o<0>(k##B##0, kp);    gload_o<1024>(k##B##1, kp);                   \
    gload_o<2048>(k##B##2, kp); gload_o<3072>(k##B##3, kp);                   \
    gload_o<0>(v##B##0, vp);    gload_o<1024>(v##B##1, vp);                   \
    gload_o<2048>(v##B##2, vp); gload_o<3072>(v##B##3, vp);                   \
    kp += 2048; vp += 2048; }

#define COMPUTE(B, T) {                                                       \
    flash_compute(k##B##0, k##B##1, k##B##2, k##B##3,                         \
                  v##B##0, v##B##1, v##B##2, v##B##3,                         \
                  qa0, qa1, qa2, qa3, S + 32 * (T), q0, qg0, hi,              \
                  o00, o01, m0, l0);                                          \
    flash_compute(k##B##0, k##B##1, k##B##2, k##B##3,                         \
                  v##B##0, v##B##1, v##B##2, v##B##3,                         \
                  qc0, qc1, qc2, qc3, S + 32 * (T), q0 + 32, qg1, hi,         \
                  o10, o11, m1, l1); }

#define STEP(CUR, NXT, T) {                                                   \
    ISSUE(NXT)                                                                \
    asm volatile("s_waitcnt vmcnt(8)" ::: "memory");                          \
    __builtin_amdgcn_sched_barrier(0);                                        \
    COMPUTE(CUR, T) }

#define STEP_LAST(CUR, T) {                                                   \
    asm volatile("s_waitcnt vmcnt(0)" ::: "memory");                          \
    __builtin_amdgcn_sched_barrier(0);                                        \
    COMPUTE(CUR, T) }

// ---------------- causal flash attention partial: frag-packed coalesced loads ----------------
__global__ __launch_bounds__(256, 2) void flash(
    const h16* __restrict__ Qf, const h16* __restrict__ Kf, const h16* __restrict__ Vf,
    h16* __restrict__ o_part, float* __restrict__ ml_part)
{
    int wid = threadIdx.x >> 6;
    int lane = threadIdx.x & 63;
    int bid = blockIdx.x;                  // grid = BATCH*NQT*5
    int quarter = bid % 5;
    int rest = bid / 5;
    int qtflip = rest & (NQT - 1);
    int batch = rest >> 6;
    int qt = NQT - 1 - qtflip;             // longest q-tiles first
    int c = quarter * 4 + wid;
    int nc = (qt >> 2) + 1;
    if (c >= nc) return;

    int q0 = qt * QBLK;
    int S = c * CHUNK;
    int l31 = lane & 31;
    int hi = lane >> 5;
    int qg0 = q0 + l31;
    int qg1 = q0 + 32 + l31;

    const h16* kp = Kf + (size_t)batch * PB + (S >> 5) * 2048 + lane * 8;
    const h16* vp = Vf + (size_t)batch * PB + (S >> 5) * 2048 + lane * 8;

    // Q fragments for both 32-row groups (coalesced; drained by first STEP's vmcnt(8))
    h16x8 qa0, qa1, qa2, qa3, qc0, qc1, qc2, qc3;
    {
        const h16* qp = Qf + (size_t)batch * PB + (q0 >> 5) * 2048 + lane * 8;
        gload_o<0>(qa0, qp); gload_o<1024>(qa1, qp);
        gload_o<2048>(qa2, qp); gload_o<3072>(qa3, qp);
        const h16* qp2 = qp + 2048;
        gload_o<0>(qc0, qp2); gload_o<1024>(qc1, qp2);
        gload_o<2048>(qc2, qp2); gload_o<3072>(qc3, qp2);
    }

    h16x8 kA0, kA1, kA2, kA3, vA0, vA1, vA2, vA3;
    h16x8 kB0, kB1, kB2, kB3, vB0, vB1, vB2, vB3;

    f32x16 o00 = {}, o01 = {}, o10 = {}, o11 = {};
    float m0 = -1e30f, l0 = 0.f, m1 = -1e30f, l1 = 0.f;

    ISSUE(A)               // prologue: 8 Q + 8 tile0 in flight

    STEP(A, B, 0)          // issue tile1 -> 24 out; vmcnt(8) = Q+tile0 done
    STEP(B, A, 1)
    STEP(A, B, 2)
    STEP(B, A, 3)
    STEP(A, B, 4)
    STEP(B, A, 5)
    STEP(A, B, 6)
    STEP_LAST(B, 7)

    // write l-normalized partials (f16) + (m, l) f32 for both groups
    size_t slot = (size_t)batch * BSLOT + slot_base(qt) + c;
    h16* opb = o_part + slot * (QBLK * 64);
    {
        float inv = 1.f / l0;
        h16* op = opb + l31 * 64;
        #pragma unroll
        for (int q = 0; q < 4; q++) {
            h16x4 pk0, pk1;
            #pragma unroll
            for (int i = 0; i < 4; i++) {
                pk0[i] = (h16)(o00[4 * q + i] * inv);
                pk1[i] = (h16)(o01[4 * q + i] * inv);
            }
            *(h16x4*)(op + 8 * q + 4 * hi) = pk0;
            *(h16x4*)(op + 32 + 8 * q + 4 * hi) = pk1;
        }
    }
    {
        float inv = 1.f / l1;
        h16* op = opb + (32 + l31) * 64;
        #pragma unroll
        for (int q = 0; q < 4; q++) {
            h16x4 pk0, pk1;
            #pragma unroll
            for (int i = 0; i < 4; i++) {
                pk0[i] = (h16)(o10[4 * q + i] * inv);
                pk1[i] = (h16)(o11[4 * q + i] * inv);
            }
            *(h16x4*)(op + 8 * q + 4 * hi) = pk0;
            *(h16x4*)(op + 32 + 8 * q + 4 * hi) = pk1;
        }
    }
    if (hi == 0) {
        ml_part[slot * 128 + l31 * 2] = m0;
        ml_part[slot * 128 + l31 * 2 + 1] = l0;
        ml_part[slot * 128 + (32 + l31) * 2] = m1;
        ml_part[slot * 128 + (32 + l31) * 2 + 1] = l1;
    }
}

// ---------------- combine partials: one block per (batch, qt, row-half of 32) ----------------
__global__ __launch_bounds__(256) void combine(
    const h16* __restrict__ o_part, const float* __restrict__ ml_part,
    float* __restrict__ out)
{
    int bid = blockIdx.x;           // BATCH*NQT*2
    int rh = bid & 1;
    int tile = bid >> 1;
    int batch = tile >> 6;
    int qt = tile & (NQT - 1);
    int q0 = qt * QBLK;
    int nc = (qt >> 2) + 1;
    int col = threadIdx.x & 63;
    int rg = threadIdx.x >> 6;      // 0..3
    size_t base = (size_t)batch * BSLOT + slot_base(qt);

    #pragma unroll
    for (int j = 0; j < 8; j++) {
        int r = rh * 32 + rg * 8 + j;
        float M = -1e30f;
        for (int c = 0; c < nc; c++)
            M = fmaxf(M, ml_part[(base + c) * 128 + r * 2]);
        float L = 0.f, acc = 0.f;
        for (int c = 0; c < nc; c++) {
            float mc = ml_part[(base + c) * 128 + r * 2];
            float lc = ml_part[(base + c) * 128 + r * 2 + 1];
            float wgt = __expf(mc - M) * lc;
            L += wgt;
            acc += wgt * (float)o_part[(base + c) * (QBLK * 64) + r * 64 + col];
        }
        out[((size_t)batch * SEQ + q0 + r) * HDIM + col] = acc / L;
    }
}

extern "C" void kernel_launch(void* const* d_in, const int* in_sizes, int n_in,
                              void* d_out, int out_size, void* d_ws, size_t ws_size,
                              hipStream_t stream) {
    const float* x  = (const float*)d_in[0];
    const float* Wq = (const float*)d_in[1];
    const float* bq = (const float*)d_in[2];
    const float* Wk = (const float*)d_in[3];
    const float* bk = (const float*)d_in[4];
    const float* Wv = (const float*)d_in[5];
    const float* bv = (const float*)d_in[6];
    float* out = (float*)d_out;

    h16* Wf = (h16*)d_ws;
    h16* Qf = Wf + WF_ELEMS;
    h16* Kf = Qf + QK_ELEMS;
    h16* Vf = Kf + QK_ELEMS;
    h16* xh = Vf + QK_ELEMS;             // 32 MB, dead after qkv_proj
    h16* o_part = xh;                    // aliases xh (flash phase)
    float* ml_part = (float*)(o_part + (size_t)NSLOT * QBLK * 64);
    // peak ws use: 0.375 + 6 + 32 MB ~= 38.4 MiB (proven in R7/R8)

    hipLaunchKernelGGL(prep, dim3(96 + 8192), dim3(256), 0, stream, Wq, Wk, Wv, x, Wf, xh);
    hipLaunchKernelGGL(qkv_proj, dim3(512), dim3(256), 0, stream,
                       xh, Wf, bq, bk, bv, Qf, Kf, Vf);
    hipLaunchKernelGGL(flash, dim3(BATCH * NQT * 5), dim3(256), 0, stream,
                       Qf, Kf, Vf, o_part, ml_part);
    hipLaunchKernelGGL(combine, dim3(BATCH * NQT * 2), dim3(256), 0, stream,
                       o_part, ml_part, out);
}

// Round 12
// 82.027 us; speedup vs baseline: 1.8773x; 1.4330x over previous
//
#include <hip/hip_runtime.h>

#define BATCH 4
#define SEQ 4096
#define DMODEL 1024
#define HDIM 64

#define QBLK 64      // q rows per wave (2 groups of 32)
#define NQT 64       // 64-row q-tiles per batch
#define CHUNK 256    // KV positions per wave
#define ITERS 8      // CHUNK / 32
#define BSLOT 544    // per-batch valid (qt,chunk) slots = sum_qt (qt/4 + 1)
#define MAXC 17      // max chunks per 64-row q-tile

typedef _Float16 h16;
typedef _Float16 h16x8 __attribute__((ext_vector_type(8)));
typedef _Float16 h16x4 __attribute__((ext_vector_type(4)));
typedef float f32x4 __attribute__((ext_vector_type(4)));
typedef float f32x16 __attribute__((ext_vector_type(16)));

#define WF_ELEMS (12 * 32 * 64 * 8)         // 196608 h16, frag-packed W
#define QK_ELEMS (BATCH * SEQ * HDIM)       // 1048576 h16 each for Q/K/V frag
#define PB 262144                            // per-batch h16 in Q/K/V frag (128 tiles * 2048)
#define NSLOT (BATCH * BSLOT)

// valid-slot prefix: qt = 4a+b -> sum_{q<qt} (q/4+1) = (a+1)(2a+b)
__device__ __forceinline__ int slot_base(int qt) {
    int a = qt >> 2, b = qt & 3;
    return (a + 1) * (2 * a + b);
}

// k-slot permutation for MFMA A/B fragments: swap bits 2<->3 (self-inverse)
__device__ __forceinline__ int kperm(int u) {
    return (u & 3) | (((u >> 2) & 1) << 3) | (((u >> 3) & 1) << 2);
}

// compiler-proof async loads; completion via explicit counted vmcnt
template<int OFF>
__device__ __forceinline__ void gload_o(h16x8& dst, const h16* p) {
    asm volatile("global_load_dwordx4 %0, %1, off offset:%2" : "=v"(dst) : "v"(p), "n"(OFF));
}

// ---------------- prep: frag-pack W (f32->f16) and x (f32->f16) ----------------
// W_frag[fg(12)][kt(32)][lane][8]: lane=(kgrp*16+ln15) holds W[32kt+8kgrp+e][16fg+ln15]
// xh_frag[mt(1024)][kt(32)][lane][8]: lane holds x[16mt+ln15][32kt+8kgrp+e]
__global__ __launch_bounds__(256) void prep(const float* __restrict__ Wq,
                                            const float* __restrict__ Wk,
                                            const float* __restrict__ Wv,
                                            const float* __restrict__ x,
                                            h16* __restrict__ Wf,
                                            h16* __restrict__ xh) {
    int b = blockIdx.x;
    if (b < 96) {
        int flat = b * 256 + threadIdx.x;     // (fg, kt, lane)
        int lane = flat & 63;
        int kt = (flat >> 6) & 31;
        int fg = flat >> 11;                  // 0..11
        int col = 16 * fg + (lane & 15);
        const float* W = (col < 64) ? Wq : (col < 128) ? Wk : Wv;
        int c = col & 63;
        int k0 = 32 * kt + 8 * (lane >> 4);
        h16x8 v;
        #pragma unroll
        for (int j = 0; j < 8; j++) v[j] = (h16)W[(size_t)(k0 + j) * 64 + c];
        *(h16x8*)(Wf + (size_t)flat * 8) = v;
        return;
    }
    size_t flat = (size_t)(b - 96) * 256 + threadIdx.x;   // (mt, kt, lane)
    int lane = (int)(flat & 63);
    int kt = (int)((flat >> 6) & 31);
    int mt = (int)(flat >> 11);               // 0..1023
    const float* xp = x + (size_t)(16 * mt + (lane & 15)) * DMODEL + 32 * kt + 8 * (lane >> 4);
    f32x4 lo = *(const f32x4*)xp;
    f32x4 hi = *(const f32x4*)(xp + 4);
    h16x8 v;
    #pragma unroll
    for (int j = 0; j < 4; j++) { v[j] = (h16)lo[j]; v[j + 4] = (h16)hi[j]; }
    *(h16x8*)(xh + flat * 8) = v;
}

// ---------------- QKV projection GEMM: frag-packed coalesced loads, quad-buffered ----------------
#define QISSUE(S, IMM)                                                        \
    gload_o<IMM>(a##S##0, ax0); gload_o<IMM>(a##S##1, ax1);                   \
    gload_o<IMM>(b##S##0, w0);  gload_o<IMM>(b##S##1, w1);                    \
    gload_o<IMM>(b##S##2, w2);

#define QCOMPUTE(S)                                                           \
    c00 = __builtin_amdgcn_mfma_f32_16x16x32_f16(a##S##0, b##S##0, c00, 0, 0, 0); \
    c01 = __builtin_amdgcn_mfma_f32_16x16x32_f16(a##S##0, b##S##1, c01, 0, 0, 0); \
    c02 = __builtin_amdgcn_mfma_f32_16x16x32_f16(a##S##0, b##S##2, c02, 0, 0, 0); \
    c10 = __builtin_amdgcn_mfma_f32_16x16x32_f16(a##S##1, b##S##0, c10, 0, 0, 0); \
    c11 = __builtin_amdgcn_mfma_f32_16x16x32_f16(a##S##1, b##S##1, c11, 0, 0, 0); \
    c12 = __builtin_amdgcn_mfma_f32_16x16x32_f16(a##S##1, b##S##2, c12, 0, 0, 0);

#define QSTEP(S, N) {                                                         \
    asm volatile("s_waitcnt vmcnt(" #N ")" ::: "memory");                     \
    __builtin_amdgcn_sched_barrier(0);                                        \
    QCOMPUTE(S)                                                               \
    QISSUE(S, 3072)                                                           \
    ax0 += 512; ax1 += 512; w0 += 512; w1 += 512; w2 += 512; }

#define QSTEP_T(S, N) {                                                       \
    asm volatile("s_waitcnt vmcnt(" #N ")" ::: "memory");                     \
    __builtin_amdgcn_sched_barrier(0);                                        \
    QCOMPUTE(S) }

__global__ __launch_bounds__(256, 2) void qkv_proj(
    const h16* __restrict__ xh, const h16* __restrict__ Wf,
    const float* __restrict__ bq, const float* __restrict__ bk, const float* __restrict__ bv,
    h16* __restrict__ Qf, h16* __restrict__ Kf, h16* __restrict__ Vf)
{
    int lane = threadIdx.x & 63;
    int w = threadIdx.x >> 6;
    int r0 = blockIdx.x * 32;
    int ln15 = lane & 15;

    // base pointers start at kt=1 (prologue offsets -1024..2048, steady +3072)
    const h16* ax0 = xh + (size_t)(2 * blockIdx.x) * 16384 + lane * 8 + 512;
    const h16* ax1 = ax0 + 16384;
    const h16* w0 = Wf + (size_t)(3 * w) * 16384 + lane * 8 + 512;
    const h16* w1 = w0 + 16384;
    const h16* w2 = w0 + 32768;

    h16x8 aA0, aA1, bA0, bA1, bA2;
    h16x8 aB0, aB1, bB0, bB1, bB2;
    h16x8 aC0, aC1, bC0, bC1, bC2;
    h16x8 aD0, aD1, bD0, bD1, bD2;
    f32x4 c00 = {}, c01 = {}, c02 = {}, c10 = {}, c11 = {}, c12 = {};

    QISSUE(A, -1024) QISSUE(B, 0) QISSUE(C, 1024) QISSUE(D, 2048)   // 20 in flight

    QSTEP(A, 15) QSTEP(B, 15) QSTEP(C, 15) QSTEP(D, 15)
    QSTEP(A, 15) QSTEP(B, 15) QSTEP(C, 15) QSTEP(D, 15)
    QSTEP(A, 15) QSTEP(B, 15) QSTEP(C, 15) QSTEP(D, 15)
    QSTEP(A, 15) QSTEP(B, 15) QSTEP(C, 15) QSTEP(D, 15)
    QSTEP(A, 15) QSTEP(B, 15) QSTEP(C, 15) QSTEP(D, 15)
    QSTEP(A, 15) QSTEP(B, 15) QSTEP(C, 15) QSTEP(D, 15)
    QSTEP(A, 15) QSTEP(B, 15) QSTEP(C, 15) QSTEP(D, 15)
    QSTEP_T(A, 15) QSTEP_T(B, 10) QSTEP_T(C, 5) QSTEP_T(D, 0)

    // epilogue: +bias, scatter-write into fragment-packed Q/K/V layouts
    f32x4 acc[2][3] = {{c00, c01, c02}, {c10, c11, c12}};
    #pragma unroll
    for (int f = 0; f < 3; f++) {
        int col = 48 * w + 16 * f + ln15;
        float bias = (col < 64) ? bq[col] : (col < 128) ? bk[col - 64] : bv[col - 128];
        #pragma unroll
        for (int m = 0; m < 2; m++) {
            #pragma unroll
            for (int i = 0; i < 4; i++) {
                int t = r0 + 16 * m + (lane >> 4) * 4 + i;
                int bb = t >> 12;
                int tt = t & (SEQ - 1);
                float v = acc[m][f][i] + bias;
                if (col < 64) {          // Q: frag[tq][d][hi*32+l31][e], pre-scaled
                    int d = col >> 4, hh = (col >> 3) & 1, e = col & 7;
                    Qf[(size_t)bb * PB + (tt >> 5) * 2048 + d * 512 +
                       (hh * 32 + (tt & 31)) * 8 + e] = (h16)(v * 0.125f);
                } else if (col < 128) {  // K
                    int ck = col - 64;
                    int d = ck >> 4, hh = (ck >> 3) & 1, e = ck & 7;
                    Kf[(size_t)bb * PB + (tt >> 5) * 2048 + d * 512 +
                       (hh * 32 + (tt & 31)) * 8 + e] = (h16)v;
                } else {                 // V: kperm folded into index
                    int h = col - 128;
                    int tp = (tt & ~15) | kperm(tt & 15);
                    int j = ((h >> 5) << 1) | ((tp >> 4) & 1);
                    Vf[(size_t)bb * PB + (tp >> 5) * 2048 + j * 512 +
                       (((tp >> 3) & 1) * 32 + (h & 31)) * 8 + (tp & 7)] = (h16)v;
                }
            }
        }
    }
}

// ---------------- flash compute step (one 32-row q-group): QK -> softmax -> PV ----------------
__device__ __forceinline__ void flash_compute(
    h16x8 K0, h16x8 K1, h16x8 K2, h16x8 K3,
    h16x8 V0, h16x8 V1, h16x8 V2, h16x8 V3,
    h16x8 q0v, h16x8 q1v, h16x8 q2v, h16x8 q3v,
    int kt0, int q0g, int qg, int hi,
    f32x16& o0, f32x16& o1, float& m_i, float& l_i)
{
    f32x16 s = {};
    __builtin_amdgcn_s_setprio(1);
    s = __builtin_amdgcn_mfma_f32_32x32x16_f16(K0, q0v, s, 0, 0, 0);
    s = __builtin_amdgcn_mfma_f32_32x32x16_f16(K1, q1v, s, 0, 0, 0);
    s = __builtin_amdgcn_mfma_f32_32x32x16_f16(K2, q2v, s, 0, 0, 0);
    s = __builtin_amdgcn_mfma_f32_32x32x16_f16(K3, q3v, s, 0, 0, 0);
    __builtin_amdgcn_s_setprio(0);

    float sc[16];
    #pragma unroll
    for (int r = 0; r < 16; r++) sc[r] = s[r];
    if (kt0 + 31 > q0g) {
        #pragma unroll
        for (int r = 0; r < 16; r++) {
            int kg = kt0 + (r & 3) + 8 * (r >> 2) + 4 * hi;
            if (kg > qg) sc[r] = -1e30f;
        }
    }
    float tm = sc[0];
    #pragma unroll
    for (int r = 1; r < 16; r++) tm = fmaxf(tm, sc[r]);
    tm = fmaxf(tm, __shfl_xor(tm, 32));
    float mn = fmaxf(m_i, tm);
    float al = __expf(m_i - mn);
    m_i = mn;
    float p[16], rs = 0.f;
    #pragma unroll
    for (int r = 0; r < 16; r++) { p[r] = __expf(sc[r] - mn); rs += p[r]; }
    rs += __shfl_xor(rs, 32);
    l_i = l_i * al + rs;
    #pragma unroll
    for (int r = 0; r < 16; r++) { o0[r] *= al; o1[r] *= al; }

    h16x8 pb0, pb1;
    #pragma unroll
    for (int j = 0; j < 8; j++) { pb0[j] = (h16)p[j]; pb1[j] = (h16)p[8 + j]; }

    __builtin_amdgcn_s_setprio(1);
    o0 = __builtin_amdgcn_mfma_f32_32x32x16_f16(V0, pb0, o0, 0, 0, 0);
    o0 = __builtin_amdgcn_mfma_f32_32x32x16_f16(V1, pb1, o0, 0, 0, 0);
    o1 = __builtin_amdgcn_mfma_f32_32x32x16_f16(V2, pb0, o1, 0, 0, 0);
    o1 = __builtin_amdgcn_mfma_f32_32x32x16_f16(V3, pb1, o1, 0, 0, 0);
    __builtin_amdgcn_s_setprio(0);
}

// coalesced frag loads for one 32-kv tile (4 K + 4 V), then advance 4KB
#define ISSUE(B) {                                                            \
    gload_o<0>(k##B##0, kp);    gload_o<1024>(k##B##1, kp);                   \
    gload_o<2048>(k##B##2, kp); gload_o<3072>(k##B##3, kp);                   \
    gload_o<0>(v##B##0, vp);    gload_o<1024>(v##B##1, vp);                   \
    gload_o<2048>(v##B##2, vp); gload_o<3072>(v##B##3, vp);                   \
    kp += 2048; vp += 2048; }

#define COMPUTE(B, T) {                                                       \
    flash_compute(k##B##0, k##B##1, k##B##2, k##B##3,                         \
                  v##B##0, v##B##1, v##B##2, v##B##3,                         \
                  qa0, qa1, qa2, qa3, S + 32 * (T), q0, qg0, hi,              \
                  o00, o01, m0, l0);                                          \
    flash_compute(k##B##0, k##B##1, k##B##2, k##B##3,                         \
                  v##B##0, v##B##1, v##B##2, v##B##3,                         \
                  qc0, qc1, qc2, qc3, S + 32 * (T), q0 + 32, qg1, hi,         \
                  o10, o11, m1, l1); }

#define STEP(CUR, NXT, T) {                                                   \
    ISSUE(NXT)                                                                \
    asm volatile("s_waitcnt vmcnt(8)" ::: "memory");                          \
    __builtin_amdgcn_sched_barrier(0);                                        \
    COMPUTE(CUR, T) }

#define STEP_LAST(CUR, T) {                                                   \
    asm volatile("s_waitcnt vmcnt(0)" ::: "memory");                          \
    __builtin_amdgcn_sched_barrier(0);                                        \
    COMPUTE(CUR, T) }

// ---------------- causal flash attention partial: frag-packed coalesced loads ----------------
__global__ __launch_bounds__(256, 2) void flash(
    const h16* __restrict__ Qf, const h16* __restrict__ Kf, const h16* __restrict__ Vf,
    h16* __restrict__ o_part, float* __restrict__ ml_part)
{
    int wid = threadIdx.x >> 6;
    int lane = threadIdx.x & 63;
    int bid = blockIdx.x;                  // grid = BATCH*NQT*5
    int quarter = bid % 5;
    int rest = bid / 5;
    int qtflip = rest & (NQT - 1);
    int batch = rest >> 6;
    int qt = NQT - 1 - qtflip;             // longest q-tiles first
    int c = quarter * 4 + wid;
    int nc = (qt >> 2) + 1;
    if (c >= nc) return;

    int q0 = qt * QBLK;
    int S = c * CHUNK;
    int l31 = lane & 31;
    int hi = lane >> 5;
    int qg0 = q0 + l31;
    int qg1 = q0 + 32 + l31;

    const h16* kp = Kf + (size_t)batch * PB + (S >> 5) * 2048 + lane * 8;
    const h16* vp = Vf + (size_t)batch * PB + (S >> 5) * 2048 + lane * 8;

    // Q fragments for both 32-row groups (coalesced; drained by first STEP's vmcnt(8))
    h16x8 qa0, qa1, qa2, qa3, qc0, qc1, qc2, qc3;
    {
        const h16* qp = Qf + (size_t)batch * PB + (q0 >> 5) * 2048 + lane * 8;
        gload_o<0>(qa0, qp); gload_o<1024>(qa1, qp);
        gload_o<2048>(qa2, qp); gload_o<3072>(qa3, qp);
        const h16* qp2 = qp + 2048;
        gload_o<0>(qc0, qp2); gload_o<1024>(qc1, qp2);
        gload_o<2048>(qc2, qp2); gload_o<3072>(qc3, qp2);
    }

    h16x8 kA0, kA1, kA2, kA3, vA0, vA1, vA2, vA3;
    h16x8 kB0, kB1, kB2, kB3, vB0, vB1, vB2, vB3;

    f32x16 o00 = {}, o01 = {}, o10 = {}, o11 = {};
    float m0 = -1e30f, l0 = 0.f, m1 = -1e30f, l1 = 0.f;

    ISSUE(A)               // prologue: 8 Q + 8 tile0 in flight

    STEP(A, B, 0)          // issue tile1 -> 24 out; vmcnt(8) = Q+tile0 done
    STEP(B, A, 1)
    STEP(A, B, 2)
    STEP(B, A, 3)
    STEP(A, B, 4)
    STEP(B, A, 5)
    STEP(A, B, 6)
    STEP_LAST(B, 7)

    // write l-normalized partials (f16) + (m, l) f32 for both groups
    size_t slot = (size_t)batch * BSLOT + slot_base(qt) + c;
    h16* opb = o_part + slot * (QBLK * 64);
    {
        float inv = 1.f / l0;
        h16* op = opb + l31 * 64;
        #pragma unroll
        for (int q = 0; q < 4; q++) {
            h16x4 pk0, pk1;
            #pragma unroll
            for (int i = 0; i < 4; i++) {
                pk0[i] = (h16)(o00[4 * q + i] * inv);
                pk1[i] = (h16)(o01[4 * q + i] * inv);
            }
            *(h16x4*)(op + 8 * q + 4 * hi) = pk0;
            *(h16x4*)(op + 32 + 8 * q + 4 * hi) = pk1;
        }
    }
    {
        float inv = 1.f / l1;
        h16* op = opb + (32 + l31) * 64;
        #pragma unroll
        for (int q = 0; q < 4; q++) {
            h16x4 pk0, pk1;
            #pragma unroll
            for (int i = 0; i < 4; i++) {
                pk0[i] = (h16)(o10[4 * q + i] * inv);
                pk1[i] = (h16)(o11[4 * q + i] * inv);
            }
            *(h16x4*)(op + 8 * q + 4 * hi) = pk0;
            *(h16x4*)(op + 32 + 8 * q + 4 * hi) = pk1;
        }
    }
    if (hi == 0) {
        ml_part[slot * 128 + l31 * 2] = m0;
        ml_part[slot * 128 + l31 * 2 + 1] = l0;
        ml_part[slot * 128 + (32 + l31) * 2] = m1;
        ml_part[slot * 128 + (32 + l31) * 2 + 1] = l1;
    }
}

// ---------------- combine partials: LDS-staged ml, one block per 16-row quarter ----------------
__global__ __launch_bounds__(256) void combine(
    const h16* __restrict__ o_part, const float* __restrict__ ml_part,
    float* __restrict__ out)
{
    __shared__ float mlds[MAXC * 128];
    int bid = blockIdx.x;           // BATCH*NQT*4
    int rq = bid & 3;               // 16-row quarter
    int tile = bid >> 2;
    int batch = tile >> 6;
    int qt = tile & (NQT - 1);
    int q0 = qt * QBLK;
    int nc = (qt >> 2) + 1;
    size_t base = (size_t)batch * BSLOT + slot_base(qt);

    // stage the ml slab (nc x 128 floats) coalesced into LDS
    for (int i = threadIdx.x; i < nc * 128; i += 256)
        mlds[i] = ml_part[base * 128 + i];
    __syncthreads();

    int col = threadIdx.x & 63;
    int rg = threadIdx.x >> 6;      // 0..3
    #pragma unroll
    for (int j = 0; j < 4; j++) {
        int r = rq * 16 + rg * 4 + j;
        float M = -1e30f;
        for (int c = 0; c < nc; c++)
            M = fmaxf(M, mlds[c * 128 + r * 2]);
        const h16* op = o_part + base * (QBLK * 64) + r * 64 + col;
        float L = 0.f, acc0 = 0.f, acc1 = 0.f;
        int c = 0;
        for (; c + 2 <= nc; c += 2) {
            float w0 = __expf(mlds[c * 128 + r * 2] - M) * mlds[c * 128 + r * 2 + 1];
            float w1 = __expf(mlds[(c + 1) * 128 + r * 2] - M) * mlds[(c + 1) * 128 + r * 2 + 1];
            L += w0 + w1;
            acc0 += w0 * (float)op[(size_t)c * (QBLK * 64)];
            acc1 += w1 * (float)op[(size_t)(c + 1) * (QBLK * 64)];
        }
        if (c < nc) {
            float w0 = __expf(mlds[c * 128 + r * 2] - M) * mlds[c * 128 + r * 2 + 1];
            L += w0;
            acc0 += w0 * (float)op[(size_t)c * (QBLK * 64)];
        }
        out[((size_t)batch * SEQ + q0 + r) * HDIM + col] = (acc0 + acc1) / L;
    }
}

extern "C" void kernel_launch(void* const* d_in, const int* in_sizes, int n_in,
                              void* d_out, int out_size, void* d_ws, size_t ws_size,
                              hipStream_t stream) {
    const float* x  = (const float*)d_in[0];
    const float* Wq = (const float*)d_in[1];
    const float* bq = (const float*)d_in[2];
    const float* Wk = (const float*)d_in[3];
    const float* bk = (const float*)d_in[4];
    const float* Wv = (const float*)d_in[5];
    const float* bv = (const float*)d_in[6];
    float* out = (float*)d_out;

    h16* Wf = (h16*)d_ws;
    h16* Qf = Wf + WF_ELEMS;
    h16* Kf = Qf + QK_ELEMS;
    h16* Vf = Kf + QK_ELEMS;
    h16* xh = Vf + QK_ELEMS;             // 32 MB, dead after qkv_proj
    h16* o_part = xh;                    // aliases xh (flash phase)
    float* ml_part = (float*)(o_part + (size_t)NSLOT * QBLK * 64);
    // peak ws use ~= 38.4 MiB (proven in R7/R8)

    hipLaunchKernelGGL(prep, dim3(96 + 8192), dim3(256), 0, stream, Wq, Wk, Wv, x, Wf, xh);
    hipLaunchKernelGGL(qkv_proj, dim3(512), dim3(256), 0, stream,
                       xh, Wf, bq, bk, bv, Qf, Kf, Vf);
    hipLaunchKernelGGL(flash, dim3(BATCH * NQT * 5), dim3(256), 0, stream,
                       Qf, Kf, Vf, o_part, ml_part);
    hipLaunchKernelGGL(combine, dim3(BATCH * NQT * 4), dim3(256), 0, stream,
                       o_part, ml_part, out);
}

// Round 13
// 74.881 us; speedup vs baseline: 2.0565x; 1.0954x over previous
//
#include <hip/hip_runtime.h>

#define BATCH 4
#define SEQ 4096
#define DMODEL 1024
#define HDIM 64

#define QBLK 64      // q rows per wave (2 groups of 32)
#define NQT 64       // 64-row q-tiles per batch
#define CHUNK 256    // KV positions per wave
#define ITERS 8      // CHUNK / 32
#define BSLOT 544    // per-batch valid (qt,chunk) slots = sum_qt (qt/4 + 1)
#define MAXC 17      // max chunks per 64-row q-tile

typedef _Float16 h16;
typedef _Float16 h16x8 __attribute__((ext_vector_type(8)));
typedef _Float16 h16x4 __attribute__((ext_vector_type(4)));
typedef float f32x4 __attribute__((ext_vector_type(4)));
typedef float f32x16 __attribute__((ext_vector_type(16)));

#define WF_ELEMS (12 * 32 * 64 * 8)         // 196608 h16, frag-packed W
#define QK_ELEMS (BATCH * SEQ * HDIM)       // 1048576 h16 each for Q/K/V frag
#define PB 262144                            // per-batch h16 in Q/K/V frag (128 tiles * 2048)
#define NSLOT (BATCH * BSLOT)

// valid-slot prefix: qt = 4a+b -> sum_{q<qt} (q/4+1) = (a+1)(2a+b)
__device__ __forceinline__ int slot_base(int qt) {
    int a = qt >> 2, b = qt & 3;
    return (a + 1) * (2 * a + b);
}

// k-slot permutation for MFMA A/B fragments: swap bits 2<->3 (self-inverse)
__device__ __forceinline__ int kperm(int u) {
    return (u & 3) | (((u >> 2) & 1) << 3) | (((u >> 3) & 1) << 2);
}

// compiler-proof async loads; completion via explicit counted vmcnt
template<int OFF>
__device__ __forceinline__ void gload_o(h16x8& dst, const h16* p) {
    asm volatile("global_load_dwordx4 %0, %1, off offset:%2" : "=v"(dst) : "v"(p), "n"(OFF));
}

// ---------------- prep: frag-pack W (f32->f16) and x (f32->f16) ----------------
// W_frag[fg(12)][kt(32)][lane][8]: lane=(kgrp*16+ln15) holds W[32kt+8kgrp+e][16fg+ln15]
// xh_frag[mt(1024)][kt(32)][lane][8]: lane holds x[16mt+ln15][32kt+8kgrp+e]
__global__ __launch_bounds__(256) void prep(const float* __restrict__ Wq,
                                            const float* __restrict__ Wk,
                                            const float* __restrict__ Wv,
                                            const float* __restrict__ x,
                                            h16* __restrict__ Wf,
                                            h16* __restrict__ xh) {
    int b = blockIdx.x;
    if (b < 96) {
        int flat = b * 256 + threadIdx.x;     // (fg, kt, lane)
        int lane = flat & 63;
        int kt = (flat >> 6) & 31;
        int fg = flat >> 11;                  // 0..11
        int col = 16 * fg + (lane & 15);
        const float* W = (col < 64) ? Wq : (col < 128) ? Wk : Wv;
        int c = col & 63;
        int k0 = 32 * kt + 8 * (lane >> 4);
        h16x8 v;
        #pragma unroll
        for (int j = 0; j < 8; j++) v[j] = (h16)W[(size_t)(k0 + j) * 64 + c];
        *(h16x8*)(Wf + (size_t)flat * 8) = v;
        return;
    }
    size_t flat = (size_t)(b - 96) * 256 + threadIdx.x;   // (mt, kt, lane)
    int lane = (int)(flat & 63);
    int kt = (int)((flat >> 6) & 31);
    int mt = (int)(flat >> 11);               // 0..1023
    const float* xp = x + (size_t)(16 * mt + (lane & 15)) * DMODEL + 32 * kt + 8 * (lane >> 4);
    f32x4 lo = *(const f32x4*)xp;
    f32x4 hi = *(const f32x4*)(xp + 4);
    h16x8 v;
    #pragma unroll
    for (int j = 0; j < 4; j++) { v[j] = (h16)lo[j]; v[j + 4] = (h16)hi[j]; }
    *(h16x8*)(xh + flat * 8) = v;
}

// ---------------- QKV projection GEMM: frag-packed coalesced loads, quad-buffered ----------------
#define QISSUE(S, IMM)                                                        \
    gload_o<IMM>(a##S##0, ax0); gload_o<IMM>(a##S##1, ax1);                   \
    gload_o<IMM>(b##S##0, w0);  gload_o<IMM>(b##S##1, w1);                    \
    gload_o<IMM>(b##S##2, w2);

#define QCOMPUTE(S)                                                           \
    c00 = __builtin_amdgcn_mfma_f32_16x16x32_f16(a##S##0, b##S##0, c00, 0, 0, 0); \
    c01 = __builtin_amdgcn_mfma_f32_16x16x32_f16(a##S##0, b##S##1, c01, 0, 0, 0); \
    c02 = __builtin_amdgcn_mfma_f32_16x16x32_f16(a##S##0, b##S##2, c02, 0, 0, 0); \
    c10 = __builtin_amdgcn_mfma_f32_16x16x32_f16(a##S##1, b##S##0, c10, 0, 0, 0); \
    c11 = __builtin_amdgcn_mfma_f32_16x16x32_f16(a##S##1, b##S##1, c11, 0, 0, 0); \
    c12 = __builtin_amdgcn_mfma_f32_16x16x32_f16(a##S##1, b##S##2, c12, 0, 0, 0);

#define QSTEP(S, N) {                                                         \
    asm volatile("s_waitcnt vmcnt(" #N ")" ::: "memory");                     \
    __builtin_amdgcn_sched_barrier(0);                                        \
    QCOMPUTE(S)                                                               \
    QISSUE(S, 3072)                                                           \
    ax0 += 512; ax1 += 512; w0 += 512; w1 += 512; w2 += 512; }

#define QSTEP_T(S, N) {                                                       \
    asm volatile("s_waitcnt vmcnt(" #N ")" ::: "memory");                     \
    __builtin_amdgcn_sched_barrier(0);                                        \
    QCOMPUTE(S) }

__global__ __launch_bounds__(256, 2) void qkv_proj(
    const h16* __restrict__ xh, const h16* __restrict__ Wf,
    const float* __restrict__ bq, const float* __restrict__ bk, const float* __restrict__ bv,
    h16* __restrict__ Qf, h16* __restrict__ Kf, h16* __restrict__ Vf)
{
    int lane = threadIdx.x & 63;
    int w = threadIdx.x >> 6;
    int r0 = blockIdx.x * 32;
    int ln15 = lane & 15;

    // base pointers start at kt=1 (prologue offsets -1024..2048, steady +3072)
    const h16* ax0 = xh + (size_t)(2 * blockIdx.x) * 16384 + lane * 8 + 512;
    const h16* ax1 = ax0 + 16384;
    const h16* w0 = Wf + (size_t)(3 * w) * 16384 + lane * 8 + 512;
    const h16* w1 = w0 + 16384;
    const h16* w2 = w0 + 32768;

    h16x8 aA0, aA1, bA0, bA1, bA2;
    h16x8 aB0, aB1, bB0, bB1, bB2;
    h16x8 aC0, aC1, bC0, bC1, bC2;
    h16x8 aD0, aD1, bD0, bD1, bD2;
    f32x4 c00 = {}, c01 = {}, c02 = {}, c10 = {}, c11 = {}, c12 = {};

    QISSUE(A, -1024) QISSUE(B, 0) QISSUE(C, 1024) QISSUE(D, 2048)   // 20 in flight

    QSTEP(A, 15) QSTEP(B, 15) QSTEP(C, 15) QSTEP(D, 15)
    QSTEP(A, 15) QSTEP(B, 15) QSTEP(C, 15) QSTEP(D, 15)
    QSTEP(A, 15) QSTEP(B, 15) QSTEP(C, 15) QSTEP(D, 15)
    QSTEP(A, 15) QSTEP(B, 15) QSTEP(C, 15) QSTEP(D, 15)
    QSTEP(A, 15) QSTEP(B, 15) QSTEP(C, 15) QSTEP(D, 15)
    QSTEP(A, 15) QSTEP(B, 15) QSTEP(C, 15) QSTEP(D, 15)
    QSTEP(A, 15) QSTEP(B, 15) QSTEP(C, 15) QSTEP(D, 15)
    QSTEP_T(A, 15) QSTEP_T(B, 10) QSTEP_T(C, 5) QSTEP_T(D, 0)

    // epilogue: +bias, scatter-write into fragment-packed Q/K/V layouts
    f32x4 acc[2][3] = {{c00, c01, c02}, {c10, c11, c12}};
    #pragma unroll
    for (int f = 0; f < 3; f++) {
        int col = 48 * w + 16 * f + ln15;
        float bias = (col < 64) ? bq[col] : (col < 128) ? bk[col - 64] : bv[col - 128];
        #pragma unroll
        for (int m = 0; m < 2; m++) {
            #pragma unroll
            for (int i = 0; i < 4; i++) {
                int t = r0 + 16 * m + (lane >> 4) * 4 + i;
                int bb = t >> 12;
                int tt = t & (SEQ - 1);
                float v = acc[m][f][i] + bias;
                if (col < 64) {          // Q: frag[tq][d][hi*32+l31][e], pre-scaled
                    int d = col >> 4, hh = (col >> 3) & 1, e = col & 7;
                    Qf[(size_t)bb * PB + (tt >> 5) * 2048 + d * 512 +
                       (hh * 32 + (tt & 31)) * 8 + e] = (h16)(v * 0.125f);
                } else if (col < 128) {  // K
                    int ck = col - 64;
                    int d = ck >> 4, hh = (ck >> 3) & 1, e = ck & 7;
                    Kf[(size_t)bb * PB + (tt >> 5) * 2048 + d * 512 +
                       (hh * 32 + (tt & 31)) * 8 + e] = (h16)v;
                } else {                 // V: kperm folded into index
                    int h = col - 128;
                    int tp = (tt & ~15) | kperm(tt & 15);
                    int j = ((h >> 5) << 1) | ((tp >> 4) & 1);
                    Vf[(size_t)bb * PB + (tp >> 5) * 2048 + j * 512 +
                       (((tp >> 3) & 1) * 32 + (h & 31)) * 8 + (tp & 7)] = (h16)v;
                }
            }
        }
    }
}

// ---------------- flash compute step (one 32-row q-group): QK -> softmax -> PV ----------------
// NOTE: no setprio inside -- the two per-tile group calls form ONE scheduling region so the
// compiler interleaves their independent MFMA/softmax chains.
__device__ __forceinline__ void flash_compute(
    h16x8 K0, h16x8 K1, h16x8 K2, h16x8 K3,
    h16x8 V0, h16x8 V1, h16x8 V2, h16x8 V3,
    h16x8 q0v, h16x8 q1v, h16x8 q2v, h16x8 q3v,
    int kt0, int q0g, int qg, int hi,
    f32x16& o0, f32x16& o1, float& m_i, float& l_i)
{
    f32x16 s = {};
    s = __builtin_amdgcn_mfma_f32_32x32x16_f16(K0, q0v, s, 0, 0, 0);
    s = __builtin_amdgcn_mfma_f32_32x32x16_f16(K1, q1v, s, 0, 0, 0);
    s = __builtin_amdgcn_mfma_f32_32x32x16_f16(K2, q2v, s, 0, 0, 0);
    s = __builtin_amdgcn_mfma_f32_32x32x16_f16(K3, q3v, s, 0, 0, 0);

    float sc[16];
    #pragma unroll
    for (int r = 0; r < 16; r++) sc[r] = s[r];
    if (kt0 + 31 > q0g) {
        #pragma unroll
        for (int r = 0; r < 16; r++) {
            int kg = kt0 + (r & 3) + 8 * (r >> 2) + 4 * hi;
            if (kg > qg) sc[r] = -1e30f;
        }
    }
    float tm = sc[0];
    #pragma unroll
    for (int r = 1; r < 16; r++) tm = fmaxf(tm, sc[r]);
    tm = fmaxf(tm, __shfl_xor(tm, 32));
    float mn = fmaxf(m_i, tm);
    float al = __expf(m_i - mn);
    m_i = mn;
    float p[16], rs = 0.f;
    #pragma unroll
    for (int r = 0; r < 16; r++) { p[r] = __expf(sc[r] - mn); rs += p[r]; }
    rs += __shfl_xor(rs, 32);
    l_i = l_i * al + rs;
    #pragma unroll
    for (int r = 0; r < 16; r++) { o0[r] *= al; o1[r] *= al; }

    h16x8 pb0, pb1;
    #pragma unroll
    for (int j = 0; j < 8; j++) { pb0[j] = (h16)p[j]; pb1[j] = (h16)p[8 + j]; }

    o0 = __builtin_amdgcn_mfma_f32_32x32x16_f16(V0, pb0, o0, 0, 0, 0);
    o0 = __builtin_amdgcn_mfma_f32_32x32x16_f16(V1, pb1, o0, 0, 0, 0);
    o1 = __builtin_amdgcn_mfma_f32_32x32x16_f16(V2, pb0, o1, 0, 0, 0);
    o1 = __builtin_amdgcn_mfma_f32_32x32x16_f16(V3, pb1, o1, 0, 0, 0);
}

// coalesced frag loads for one 32-kv tile (4 K + 4 V), then advance 4KB
#define ISSUE(B) {                                                            \
    gload_o<0>(k##B##0, kp);    gload_o<1024>(k##B##1, kp);                   \
    gload_o<2048>(k##B##2, kp); gload_o<3072>(k##B##3, kp);                   \
    gload_o<0>(v##B##0, vp);    gload_o<1024>(v##B##1, vp);                   \
    gload_o<2048>(v##B##2, vp); gload_o<3072>(v##B##3, vp);                   \
    kp += 2048; vp += 2048; }

#define COMPUTE(B, T) {                                                       \
    __builtin_amdgcn_s_setprio(1);                                            \
    flash_compute(k##B##0, k##B##1, k##B##2, k##B##3,                         \
                  v##B##0, v##B##1, v##B##2, v##B##3,                         \
                  qa0, qa1, qa2, qa3, S + 32 * (T), q0, qg0, hi,              \
                  o00, o01, m0, l0);                                          \
    flash_compute(k##B##0, k##B##1, k##B##2, k##B##3,                         \
                  v##B##0, v##B##1, v##B##2, v##B##3,                         \
                  qc0, qc1, qc2, qc3, S + 32 * (T), q0 + 32, qg1, hi,         \
                  o10, o11, m1, l1);                                          \
    __builtin_amdgcn_s_setprio(0); }

#define STEP(CUR, NXT, T) {                                                   \
    ISSUE(NXT)                                                                \
    asm volatile("s_waitcnt vmcnt(8)" ::: "memory");                          \
    __builtin_amdgcn_sched_barrier(0);                                        \
    COMPUTE(CUR, T) }

#define STEP_LAST(CUR, T) {                                                   \
    asm volatile("s_waitcnt vmcnt(0)" ::: "memory");                          \
    __builtin_amdgcn_sched_barrier(0);                                        \
    COMPUTE(CUR, T) }

// ---------------- causal flash attention partial: frag-packed coalesced loads ----------------
__global__ __launch_bounds__(256, 2) void flash(
    const h16* __restrict__ Qf, const h16* __restrict__ Kf, const h16* __restrict__ Vf,
    h16* __restrict__ o_part, float* __restrict__ ml_part)
{
    int wid = threadIdx.x >> 6;
    int lane = threadIdx.x & 63;
    int bid = blockIdx.x;                  // grid = BATCH*NQT*5
    int quarter = bid % 5;
    int rest = bid / 5;
    int qtflip = rest & (NQT - 1);
    int batch = rest >> 6;
    int qt = NQT - 1 - qtflip;             // longest q-tiles first
    int c = quarter * 4 + wid;
    int nc = (qt >> 2) + 1;
    if (c >= nc) return;

    int q0 = qt * QBLK;
    int S = c * CHUNK;
    int l31 = lane & 31;
    int hi = lane >> 5;
    int qg0 = q0 + l31;
    int qg1 = q0 + 32 + l31;

    const h16* kp = Kf + (size_t)batch * PB + (S >> 5) * 2048 + lane * 8;
    const h16* vp = Vf + (size_t)batch * PB + (S >> 5) * 2048 + lane * 8;

    // Q fragments for both 32-row groups (coalesced; drained by first STEP's vmcnt(8))
    h16x8 qa0, qa1, qa2, qa3, qc0, qc1, qc2, qc3;
    {
        const h16* qp = Qf + (size_t)batch * PB + (q0 >> 5) * 2048 + lane * 8;
        gload_o<0>(qa0, qp); gload_o<1024>(qa1, qp);
        gload_o<2048>(qa2, qp); gload_o<3072>(qa3, qp);
        const h16* qp2 = qp + 2048;
        gload_o<0>(qc0, qp2); gload_o<1024>(qc1, qp2);
        gload_o<2048>(qc2, qp2); gload_o<3072>(qc3, qp2);
    }

    h16x8 kA0, kA1, kA2, kA3, vA0, vA1, vA2, vA3;
    h16x8 kB0, kB1, kB2, kB3, vB0, vB1, vB2, vB3;

    f32x16 o00 = {}, o01 = {}, o10 = {}, o11 = {};
    float m0 = -1e30f, l0 = 0.f, m1 = -1e30f, l1 = 0.f;

    ISSUE(A)               // prologue: 8 Q + 8 tile0 in flight

    STEP(A, B, 0)          // issue tile1 -> 24 out; vmcnt(8) = Q+tile0 done
    STEP(B, A, 1)
    STEP(A, B, 2)
    STEP(B, A, 3)
    STEP(A, B, 4)
    STEP(B, A, 5)
    STEP(A, B, 6)
    STEP_LAST(B, 7)

    // write l-normalized partials (f16) + (m, l) f32 for both groups
    size_t slot = (size_t)batch * BSLOT + slot_base(qt) + c;
    h16* opb = o_part + slot * (QBLK * 64);
    {
        float inv = 1.f / l0;
        h16* op = opb + l31 * 64;
        #pragma unroll
        for (int q = 0; q < 4; q++) {
            h16x4 pk0, pk1;
            #pragma unroll
            for (int i = 0; i < 4; i++) {
                pk0[i] = (h16)(o00[4 * q + i] * inv);
                pk1[i] = (h16)(o01[4 * q + i] * inv);
            }
            *(h16x4*)(op + 8 * q + 4 * hi) = pk0;
            *(h16x4*)(op + 32 + 8 * q + 4 * hi) = pk1;
        }
    }
    {
        float inv = 1.f / l1;
        h16* op = opb + (32 + l31) * 64;
        #pragma unroll
        for (int q = 0; q < 4; q++) {
            h16x4 pk0, pk1;
            #pragma unroll
            for (int i = 0; i < 4; i++) {
                pk0[i] = (h16)(o10[4 * q + i] * inv);
                pk1[i] = (h16)(o11[4 * q + i] * inv);
            }
            *(h16x4*)(op + 8 * q + 4 * hi) = pk0;
            *(h16x4*)(op + 32 + 8 * q + 4 * hi) = pk1;
        }
    }
    if (hi == 0) {
        ml_part[slot * 128 + l31 * 2] = m0;
        ml_part[slot * 128 + l31 * 2 + 1] = l0;
        ml_part[slot * 128 + (32 + l31) * 2] = m1;
        ml_part[slot * 128 + (32 + l31) * 2 + 1] = l1;
    }
}

// ---------------- combine partials: LDS-staged ml, 4-row ILP, chunk-inner loop ----------------
__global__ __launch_bounds__(256) void combine(
    const h16* __restrict__ o_part, const float* __restrict__ ml_part,
    float* __restrict__ out)
{
    __shared__ float mlds[MAXC * 128];
    int bid = blockIdx.x;           // BATCH*NQT*4
    int rq = bid & 3;               // 16-row quarter
    int tile = bid >> 2;
    int batch = tile >> 6;
    int qt = tile & (NQT - 1);
    int q0 = qt * QBLK;
    int nc = (qt >> 2) + 1;
    size_t base = (size_t)batch * BSLOT + slot_base(qt);

    // stage the ml slab (nc x 128 floats) coalesced into LDS
    for (int i = threadIdx.x; i < nc * 128; i += 256)
        mlds[i] = ml_part[base * 128 + i];
    __syncthreads();

    int col = threadIdx.x & 63;
    int rg = threadIdx.x >> 6;      // 0..3
    int r0 = rq * 16 + rg * 4;      // this thread's 4 rows: r0..r0+3
    const h16* op = o_part + base * (QBLK * 64) + (size_t)r0 * 64 + col;

    float M[4];
    #pragma unroll
    for (int j = 0; j < 4; j++) {
        float m = -1e30f;
        for (int c = 0; c < nc; c++) m = fmaxf(m, mlds[c * 128 + (r0 + j) * 2]);
        M[j] = m;
    }

    float L4[4] = {0.f, 0.f, 0.f, 0.f}, A4[4] = {0.f, 0.f, 0.f, 0.f};
    #pragma unroll 2
    for (int c = 0; c < nc; c++) {
        #pragma unroll
        for (int j = 0; j < 4; j++) {   // 4 independent row-streams -> 8 loads in flight
            float wt = __expf(mlds[c * 128 + (r0 + j) * 2] - M[j]) *
                       mlds[c * 128 + (r0 + j) * 2 + 1];
            L4[j] += wt;
            A4[j] += wt * (float)op[(size_t)c * (QBLK * 64) + j * 64];
        }
    }
    #pragma unroll
    for (int j = 0; j < 4; j++)
        out[((size_t)batch * SEQ + q0 + r0 + j) * HDIM + col] = A4[j] / L4[j];
}

extern "C" void kernel_launch(void* const* d_in, const int* in_sizes, int n_in,
                              void* d_out, int out_size, void* d_ws, size_t ws_size,
                              hipStream_t stream) {
    const float* x  = (const float*)d_in[0];
    const float* Wq = (const float*)d_in[1];
    const float* bq = (const float*)d_in[2];
    const float* Wk = (const float*)d_in[3];
    const float* bk = (const float*)d_in[4];
    const float* Wv = (const float*)d_in[5];
    const float* bv = (const float*)d_in[6];
    float* out = (float*)d_out;

    h16* Wf = (h16*)d_ws;
    h16* Qf = Wf + WF_ELEMS;
    h16* Kf = Qf + QK_ELEMS;
    h16* Vf = Kf + QK_ELEMS;
    h16* xh = Vf + QK_ELEMS;             // 32 MB, dead after qkv_proj
    h16* o_part = xh;                    // aliases xh (flash phase)
    float* ml_part = (float*)(o_part + (size_t)NSLOT * QBLK * 64);
    // peak ws use ~= 38.4 MiB (proven in R7/R8)

    hipLaunchKernelGGL(prep, dim3(96 + 8192), dim3(256), 0, stream, Wq, Wk, Wv, x, Wf, xh);
    hipLaunchKernelGGL(qkv_proj, dim3(512), dim3(256), 0, stream,
                       xh, Wf, bq, bk, bv, Qf, Kf, Vf);
    hipLaunchKernelGGL(flash, dim3(BATCH * NQT * 5), dim3(256), 0, stream,
                       Qf, Kf, Vf, o_part, ml_part);
    hipLaunchKernelGGL(combine, dim3(BATCH * NQT * 4), dim3(256), 0, stream,
                       o_part, ml_part, out);
}

// Round 14
// 73.872 us; speedup vs baseline: 2.0846x; 1.0137x over previous
//
#include <hip/hip_runtime.h>

#define BATCH 4
#define SEQ 4096
#define DMODEL 1024
#define HDIM 64

#define QBLK 64      // q rows per wave (2 groups of 32)
#define NQT 64       // 64-row q-tiles per batch
#define CHUNK 256    // KV positions per wave
#define ITERS 8      // CHUNK / 32
#define BSLOT 544    // per-batch valid (qt,chunk) slots = sum_qt (qt/4 + 1)
#define MAXC 17      // max chunks per 64-row q-tile

// softmax computed in exp2 space: scale = (1/8) * log2(e)
#define QSCALE 0.18033688f

typedef _Float16 h16;
typedef _Float16 h16x8 __attribute__((ext_vector_type(8)));
typedef _Float16 h16x4 __attribute__((ext_vector_type(4)));
typedef float f32x4 __attribute__((ext_vector_type(4)));
typedef float f32x16 __attribute__((ext_vector_type(16)));

#define WF_ELEMS (12 * 32 * 64 * 8)         // 196608 h16, frag-packed W
#define QK_ELEMS (BATCH * SEQ * HDIM)       // 1048576 h16 each for Q/K/V frag
#define PB 262144                            // per-batch h16 in Q/K/V frag (128 tiles * 2048)
#define NSLOT (BATCH * BSLOT)

// valid-slot prefix: qt = 4a+b -> sum_{q<qt} (q/4+1) = (a+1)(2a+b)
__device__ __forceinline__ int slot_base(int qt) {
    int a = qt >> 2, b = qt & 3;
    return (a + 1) * (2 * a + b);
}

// k-slot permutation for MFMA A/B fragments: swap bits 2<->3 (self-inverse)
__device__ __forceinline__ int kperm(int u) {
    return (u & 3) | (((u >> 2) & 1) << 3) | (((u >> 3) & 1) << 2);
}

// compiler-proof async loads; completion via explicit counted vmcnt
template<int OFF>
__device__ __forceinline__ void gload_o(h16x8& dst, const h16* p) {
    asm volatile("global_load_dwordx4 %0, %1, off offset:%2" : "=v"(dst) : "v"(p), "n"(OFF));
}

// ---------------- prep: frag-pack W (f32->f16) and x (f32->f16) ----------------
__global__ __launch_bounds__(256) void prep(const float* __restrict__ Wq,
                                            const float* __restrict__ Wk,
                                            const float* __restrict__ Wv,
                                            const float* __restrict__ x,
                                            h16* __restrict__ Wf,
                                            h16* __restrict__ xh) {
    int b = blockIdx.x;
    if (b < 96) {
        int flat = b * 256 + threadIdx.x;     // (fg, kt, lane)
        int lane = flat & 63;
        int kt = (flat >> 6) & 31;
        int fg = flat >> 11;                  // 0..11
        int col = 16 * fg + (lane & 15);
        const float* W = (col < 64) ? Wq : (col < 128) ? Wk : Wv;
        int c = col & 63;
        int k0 = 32 * kt + 8 * (lane >> 4);
        h16x8 v;
        #pragma unroll
        for (int j = 0; j < 8; j++) v[j] = (h16)W[(size_t)(k0 + j) * 64 + c];
        *(h16x8*)(Wf + (size_t)flat * 8) = v;
        return;
    }
    size_t flat = (size_t)(b - 96) * 256 + threadIdx.x;   // (mt, kt, lane)
    int lane = (int)(flat & 63);
    int kt = (int)((flat >> 6) & 31);
    int mt = (int)(flat >> 11);               // 0..1023
    const float* xp = x + (size_t)(16 * mt + (lane & 15)) * DMODEL + 32 * kt + 8 * (lane >> 4);
    f32x4 lo = *(const f32x4*)xp;
    f32x4 hi = *(const f32x4*)(xp + 4);
    h16x8 v;
    #pragma unroll
    for (int j = 0; j < 4; j++) { v[j] = (h16)lo[j]; v[j + 4] = (h16)hi[j]; }
    *(h16x8*)(xh + flat * 8) = v;
}

// ---------------- QKV projection GEMM: frag-packed coalesced loads, quad-buffered ----------------
#define QISSUE(S, IMM)                                                        \
    gload_o<IMM>(a##S##0, ax0); gload_o<IMM>(a##S##1, ax1);                   \
    gload_o<IMM>(b##S##0, w0);  gload_o<IMM>(b##S##1, w1);                    \
    gload_o<IMM>(b##S##2, w2);

#define QCOMPUTE(S)                                                           \
    c00 = __builtin_amdgcn_mfma_f32_16x16x32_f16(a##S##0, b##S##0, c00, 0, 0, 0); \
    c01 = __builtin_amdgcn_mfma_f32_16x16x32_f16(a##S##0, b##S##1, c01, 0, 0, 0); \
    c02 = __builtin_amdgcn_mfma_f32_16x16x32_f16(a##S##0, b##S##2, c02, 0, 0, 0); \
    c10 = __builtin_amdgcn_mfma_f32_16x16x32_f16(a##S##1, b##S##0, c10, 0, 0, 0); \
    c11 = __builtin_amdgcn_mfma_f32_16x16x32_f16(a##S##1, b##S##1, c11, 0, 0, 0); \
    c12 = __builtin_amdgcn_mfma_f32_16x16x32_f16(a##S##1, b##S##2, c12, 0, 0, 0);

#define QSTEP(S, N) {                                                         \
    asm volatile("s_waitcnt vmcnt(" #N ")" ::: "memory");                     \
    __builtin_amdgcn_sched_barrier(0);                                        \
    QCOMPUTE(S)                                                               \
    QISSUE(S, 3072)                                                           \
    ax0 += 512; ax1 += 512; w0 += 512; w1 += 512; w2 += 512; }

#define QSTEP_T(S, N) {                                                       \
    asm volatile("s_waitcnt vmcnt(" #N ")" ::: "memory");                     \
    __builtin_amdgcn_sched_barrier(0);                                        \
    QCOMPUTE(S) }

__global__ __launch_bounds__(256, 2) void qkv_proj(
    const h16* __restrict__ xh, const h16* __restrict__ Wf,
    const float* __restrict__ bq, const float* __restrict__ bk, const float* __restrict__ bv,
    h16* __restrict__ Qf, h16* __restrict__ Kf, h16* __restrict__ Vf)
{
    int lane = threadIdx.x & 63;
    int w = threadIdx.x >> 6;
    int r0 = blockIdx.x * 32;
    int ln15 = lane & 15;

    // base pointers start at kt=1 (prologue offsets -1024..2048, steady +3072)
    const h16* ax0 = xh + (size_t)(2 * blockIdx.x) * 16384 + lane * 8 + 512;
    const h16* ax1 = ax0 + 16384;
    const h16* w0 = Wf + (size_t)(3 * w) * 16384 + lane * 8 + 512;
    const h16* w1 = w0 + 16384;
    const h16* w2 = w0 + 32768;

    h16x8 aA0, aA1, bA0, bA1, bA2;
    h16x8 aB0, aB1, bB0, bB1, bB2;
    h16x8 aC0, aC1, bC0, bC1, bC2;
    h16x8 aD0, aD1, bD0, bD1, bD2;
    f32x4 c00 = {}, c01 = {}, c02 = {}, c10 = {}, c11 = {}, c12 = {};

    QISSUE(A, -1024) QISSUE(B, 0) QISSUE(C, 1024) QISSUE(D, 2048)   // 20 in flight

    QSTEP(A, 15) QSTEP(B, 15) QSTEP(C, 15) QSTEP(D, 15)
    QSTEP(A, 15) QSTEP(B, 15) QSTEP(C, 15) QSTEP(D, 15)
    QSTEP(A, 15) QSTEP(B, 15) QSTEP(C, 15) QSTEP(D, 15)
    QSTEP(A, 15) QSTEP(B, 15) QSTEP(C, 15) QSTEP(D, 15)
    QSTEP(A, 15) QSTEP(B, 15) QSTEP(C, 15) QSTEP(D, 15)
    QSTEP(A, 15) QSTEP(B, 15) QSTEP(C, 15) QSTEP(D, 15)
    QSTEP(A, 15) QSTEP(B, 15) QSTEP(C, 15) QSTEP(D, 15)
    QSTEP_T(A, 15) QSTEP_T(B, 10) QSTEP_T(C, 5) QSTEP_T(D, 0)

    // epilogue: +bias, scatter-write into fragment-packed Q/K/V layouts
    f32x4 acc[2][3] = {{c00, c01, c02}, {c10, c11, c12}};
    #pragma unroll
    for (int f = 0; f < 3; f++) {
        int col = 48 * w + 16 * f + ln15;
        float bias = (col < 64) ? bq[col] : (col < 128) ? bk[col - 64] : bv[col - 128];
        #pragma unroll
        for (int m = 0; m < 2; m++) {
            #pragma unroll
            for (int i = 0; i < 4; i++) {
                int t = r0 + 16 * m + (lane >> 4) * 4 + i;
                int bb = t >> 12;
                int tt = t & (SEQ - 1);
                float v = acc[m][f][i] + bias;
                if (col < 64) {          // Q: frag[tq][d][hi*32+l31][e], exp2-space pre-scale
                    int d = col >> 4, hh = (col >> 3) & 1, e = col & 7;
                    Qf[(size_t)bb * PB + (tt >> 5) * 2048 + d * 512 +
                       (hh * 32 + (tt & 31)) * 8 + e] = (h16)(v * QSCALE);
                } else if (col < 128) {  // K
                    int ck = col - 64;
                    int d = ck >> 4, hh = (ck >> 3) & 1, e = ck & 7;
                    Kf[(size_t)bb * PB + (tt >> 5) * 2048 + d * 512 +
                       (hh * 32 + (tt & 31)) * 8 + e] = (h16)v;
                } else {                 // V: kperm folded into index
                    int h = col - 128;
                    int tp = (tt & ~15) | kperm(tt & 15);
                    int j = ((h >> 5) << 1) | ((tp >> 4) & 1);
                    Vf[(size_t)bb * PB + (tp >> 5) * 2048 + j * 512 +
                       (((tp >> 3) & 1) * 32 + (h & 31)) * 8 + (tp & 7)] = (h16)v;
                }
            }
        }
    }
}

// ---------------- flash compute step (one 32-row q-group): QK -> softmax -> PV ----------------
// exp2-space softmax (scale folded into Q); T13 defer-rescale: skip o-rescale when the
// tile max doesn't exceed the running max by more than 8 (p then bounded by 2^8, f16-safe).
__device__ __forceinline__ void flash_compute(
    h16x8 K0, h16x8 K1, h16x8 K2, h16x8 K3,
    h16x8 V0, h16x8 V1, h16x8 V2, h16x8 V3,
    h16x8 q0v, h16x8 q1v, h16x8 q2v, h16x8 q3v,
    int kt0, int q0g, int qg, int hi,
    f32x16& o0, f32x16& o1, float& m_i, float& l_i)
{
    f32x16 s = {};
    s = __builtin_amdgcn_mfma_f32_32x32x16_f16(K0, q0v, s, 0, 0, 0);
    s = __builtin_amdgcn_mfma_f32_32x32x16_f16(K1, q1v, s, 0, 0, 0);
    s = __builtin_amdgcn_mfma_f32_32x32x16_f16(K2, q2v, s, 0, 0, 0);
    s = __builtin_amdgcn_mfma_f32_32x32x16_f16(K3, q3v, s, 0, 0, 0);

    float sc[16];
    #pragma unroll
    for (int r = 0; r < 16; r++) sc[r] = s[r];
    if (kt0 + 31 > q0g) {
        #pragma unroll
        for (int r = 0; r < 16; r++) {
            int kg = kt0 + (r & 3) + 8 * (r >> 2) + 4 * hi;
            if (kg > qg) sc[r] = -1e30f;
        }
    }
    float tm = sc[0];
    #pragma unroll
    for (int r = 1; r < 16; r++) tm = fmaxf(tm, sc[r]);
    tm = fmaxf(tm, __shfl_xor(tm, 32));

    if (!__all(tm - m_i <= 8.f)) {       // rescale only when max actually grows
        float mn = fmaxf(m_i, tm);
        float al = exp2f(m_i - mn);
        m_i = mn;
        l_i *= al;
        #pragma unroll
        for (int r = 0; r < 16; r++) { o0[r] *= al; o1[r] *= al; }
    }

    float p[16], rs = 0.f;
    #pragma unroll
    for (int r = 0; r < 16; r++) { p[r] = exp2f(sc[r] - m_i); rs += p[r]; }
    rs += __shfl_xor(rs, 32);
    l_i += rs;

    h16x8 pb0, pb1;
    #pragma unroll
    for (int j = 0; j < 8; j++) { pb0[j] = (h16)p[j]; pb1[j] = (h16)p[8 + j]; }

    o0 = __builtin_amdgcn_mfma_f32_32x32x16_f16(V0, pb0, o0, 0, 0, 0);
    o0 = __builtin_amdgcn_mfma_f32_32x32x16_f16(V1, pb1, o0, 0, 0, 0);
    o1 = __builtin_amdgcn_mfma_f32_32x32x16_f16(V2, pb0, o1, 0, 0, 0);
    o1 = __builtin_amdgcn_mfma_f32_32x32x16_f16(V3, pb1, o1, 0, 0, 0);
}

// coalesced frag loads for one 32-kv tile (4 K + 4 V), then advance 4KB
#define ISSUE(B) {                                                            \
    gload_o<0>(k##B##0, kp);    gload_o<1024>(k##B##1, kp);                   \
    gload_o<2048>(k##B##2, kp); gload_o<3072>(k##B##3, kp);                   \
    gload_o<0>(v##B##0, vp);    gload_o<1024>(v##B##1, vp);                   \
    gload_o<2048>(v##B##2, vp); gload_o<3072>(v##B##3, vp);                   \
    kp += 2048; vp += 2048; }

#define COMPUTE(B, T) {                                                       \
    __builtin_amdgcn_s_setprio(1);                                            \
    flash_compute(k##B##0, k##B##1, k##B##2, k##B##3,                         \
                  v##B##0, v##B##1, v##B##2, v##B##3,                         \
                  qa0, qa1, qa2, qa3, S + 32 * (T), q0, qg0, hi,              \
                  o00, o01, m0, l0);                                          \
    flash_compute(k##B##0, k##B##1, k##B##2, k##B##3,                         \
                  v##B##0, v##B##1, v##B##2, v##B##3,                         \
                  qc0, qc1, qc2, qc3, S + 32 * (T), q0 + 32, qg1, hi,         \
                  o10, o11, m1, l1);                                          \
    __builtin_amdgcn_s_setprio(0); }

#define STEP(CUR, NXT, T) {                                                   \
    ISSUE(NXT)                                                                \
    asm volatile("s_waitcnt vmcnt(8)" ::: "memory");                          \
    __builtin_amdgcn_sched_barrier(0);                                        \
    COMPUTE(CUR, T) }

#define STEP_LAST(CUR, T) {                                                   \
    asm volatile("s_waitcnt vmcnt(0)" ::: "memory");                          \
    __builtin_amdgcn_sched_barrier(0);                                        \
    COMPUTE(CUR, T) }

// ---------------- causal flash attention partial: frag-packed coalesced loads ----------------
__global__ __launch_bounds__(256, 2) void flash(
    const h16* __restrict__ Qf, const h16* __restrict__ Kf, const h16* __restrict__ Vf,
    h16* __restrict__ o_part, float* __restrict__ ml_part)
{
    int wid = threadIdx.x >> 6;
    int lane = threadIdx.x & 63;
    int bid = blockIdx.x;                  // grid = BATCH*NQT*5
    int quarter = bid % 5;
    int rest = bid / 5;
    int qtflip = rest & (NQT - 1);
    int batch = rest >> 6;
    int qt = NQT - 1 - qtflip;             // longest q-tiles first
    int c = quarter * 4 + wid;
    int nc = (qt >> 2) + 1;
    if (c >= nc) return;

    int q0 = qt * QBLK;
    int S = c * CHUNK;
    int l31 = lane & 31;
    int hi = lane >> 5;
    int qg0 = q0 + l31;
    int qg1 = q0 + 32 + l31;

    const h16* kp = Kf + (size_t)batch * PB + (S >> 5) * 2048 + lane * 8;
    const h16* vp = Vf + (size_t)batch * PB + (S >> 5) * 2048 + lane * 8;

    // Q fragments for both 32-row groups (coalesced; drained by first STEP's vmcnt(8))
    h16x8 qa0, qa1, qa2, qa3, qc0, qc1, qc2, qc3;
    {
        const h16* qp = Qf + (size_t)batch * PB + (q0 >> 5) * 2048 + lane * 8;
        gload_o<0>(qa0, qp); gload_o<1024>(qa1, qp);
        gload_o<2048>(qa2, qp); gload_o<3072>(qa3, qp);
        const h16* qp2 = qp + 2048;
        gload_o<0>(qc0, qp2); gload_o<1024>(qc1, qp2);
        gload_o<2048>(qc2, qp2); gload_o<3072>(qc3, qp2);
    }

    h16x8 kA0, kA1, kA2, kA3, vA0, vA1, vA2, vA3;
    h16x8 kB0, kB1, kB2, kB3, vB0, vB1, vB2, vB3;

    f32x16 o00 = {}, o01 = {}, o10 = {}, o11 = {};
    float m0 = -1e30f, l0 = 0.f, m1 = -1e30f, l1 = 0.f;

    ISSUE(A)               // prologue: 8 Q + 8 tile0 in flight

    STEP(A, B, 0)          // issue tile1 -> 24 out; vmcnt(8) = Q+tile0 done
    STEP(B, A, 1)
    STEP(A, B, 2)
    STEP(B, A, 3)
    STEP(A, B, 4)
    STEP(B, A, 5)
    STEP(A, B, 6)
    STEP_LAST(B, 7)

    // write l-normalized partials (f16) + (m, l) f32 for both groups
    size_t slot = (size_t)batch * BSLOT + slot_base(qt) + c;
    h16* opb = o_part + slot * (QBLK * 64);
    {
        float inv = 1.f / l0;
        h16* op = opb + l31 * 64;
        #pragma unroll
        for (int q = 0; q < 4; q++) {
            h16x4 pk0, pk1;
            #pragma unroll
            for (int i = 0; i < 4; i++) {
                pk0[i] = (h16)(o00[4 * q + i] * inv);
                pk1[i] = (h16)(o01[4 * q + i] * inv);
            }
            *(h16x4*)(op + 8 * q + 4 * hi) = pk0;
            *(h16x4*)(op + 32 + 8 * q + 4 * hi) = pk1;
        }
    }
    {
        float inv = 1.f / l1;
        h16* op = opb + (32 + l31) * 64;
        #pragma unroll
        for (int q = 0; q < 4; q++) {
            h16x4 pk0, pk1;
            #pragma unroll
            for (int i = 0; i < 4; i++) {
                pk0[i] = (h16)(o10[4 * q + i] * inv);
                pk1[i] = (h16)(o11[4 * q + i] * inv);
            }
            *(h16x4*)(op + 8 * q + 4 * hi) = pk0;
            *(h16x4*)(op + 32 + 8 * q + 4 * hi) = pk1;
        }
    }
    if (hi == 0) {
        ml_part[slot * 128 + l31 * 2] = m0;
        ml_part[slot * 128 + l31 * 2 + 1] = l0;
        ml_part[slot * 128 + (32 + l31) * 2] = m1;
        ml_part[slot * 128 + (32 + l31) * 2 + 1] = l1;
    }
}

// ---------------- combine partials: LDS ml, thread=(row, 4 cols), vectorized h16x4 ----------------
__global__ __launch_bounds__(256) void combine(
    const h16* __restrict__ o_part, const float* __restrict__ ml_part,
    float* __restrict__ out)
{
    __shared__ float mlds[MAXC * 128];
    int bid = blockIdx.x;           // BATCH*NQT*4
    int rq = bid & 3;               // 16-row quarter
    int tile = bid >> 2;
    int batch = tile >> 6;
    int qt = tile & (NQT - 1);
    int q0 = qt * QBLK;
    int nc = (qt >> 2) + 1;
    size_t base = (size_t)batch * BSLOT + slot_base(qt);

    // stage the ml slab (nc x 128 floats) coalesced into LDS
    for (int i = threadIdx.x; i < nc * 128; i += 256)
        mlds[i] = ml_part[base * 128 + i];
    __syncthreads();

    int r = rq * 16 + (threadIdx.x >> 4);   // this thread's row
    int c4 = (threadIdx.x & 15) * 4;        // 4 consecutive head-cols

    float M = -1e30f;
    for (int c = 0; c < nc; c++) M = fmaxf(M, mlds[c * 128 + r * 2]);

    const h16* op = o_part + base * (QBLK * 64) + r * 64 + c4;
    float L = 0.f;
    f32x4 A = {};
    #pragma unroll 4
    for (int c = 0; c < nc; c++) {          // 8B vector load per chunk, 4-deep pipelined
        float wt = exp2f(mlds[c * 128 + r * 2] - M) * mlds[c * 128 + r * 2 + 1];
        L += wt;
        h16x4 v = *(const h16x4*)(op + (size_t)c * (QBLK * 64));
        A[0] += wt * (float)v[0];
        A[1] += wt * (float)v[1];
        A[2] += wt * (float)v[2];
        A[3] += wt * (float)v[3];
    }
    f32x4 o;
    float inv = 1.f / L;
    #pragma unroll
    for (int j = 0; j < 4; j++) o[j] = A[j] * inv;
    *(f32x4*)(out + ((size_t)batch * SEQ + q0 + r) * HDIM + c4) = o;
}

extern "C" void kernel_launch(void* const* d_in, const int* in_sizes, int n_in,
                              void* d_out, int out_size, void* d_ws, size_t ws_size,
                              hipStream_t stream) {
    const float* x  = (const float*)d_in[0];
    const float* Wq = (const float*)d_in[1];
    const float* bq = (const float*)d_in[2];
    const float* Wk = (const float*)d_in[3];
    const float* bk = (const float*)d_in[4];
    const float* Wv = (const float*)d_in[5];
    const float* bv = (const float*)d_in[6];
    float* out = (float*)d_out;

    h16* Wf = (h16*)d_ws;
    h16* Qf = Wf + WF_ELEMS;
    h16* Kf = Qf + QK_ELEMS;
    h16* Vf = Kf + QK_ELEMS;
    h16* xh = Vf + QK_ELEMS;             // 32 MB, dead after qkv_proj
    h16* o_part = xh;                    // aliases xh (flash phase)
    float* ml_part = (float*)(o_part + (size_t)NSLOT * QBLK * 64);
    // peak ws use ~= 38.4 MiB (proven in R7/R8)

    hipLaunchKernelGGL(prep, dim3(96 + 8192), dim3(256), 0, stream, Wq, Wk, Wv, x, Wf, xh);
    hipLaunchKernelGGL(qkv_proj, dim3(512), dim3(256), 0, stream,
                       xh, Wf, bq, bk, bv, Qf, Kf, Vf);
    hipLaunchKernelGGL(flash, dim3(BATCH * NQT * 5), dim3(256), 0, stream,
                       Qf, Kf, Vf, o_part, ml_part);
    hipLaunchKernelGGL(combine, dim3(BATCH * NQT * 4), dim3(256), 0, stream,
                       o_part, ml_part, out);
}

// Round 15
// 71.759 us; speedup vs baseline: 2.1459x; 1.0294x over previous
//
#include <hip/hip_runtime.h>

#define BATCH 4
#define SEQ 4096
#define DMODEL 1024
#define HDIM 64

#define QBLK 64      // q rows per wave (2 groups of 32)
#define NQT 64       // 64-row q-tiles per batch
#define CHUNK 256    // KV positions per wave
#define ITERS 8      // CHUNK / 32
#define BSLOT 544    // per-batch valid (qt,chunk) slots = sum_qt (qt/4 + 1)
#define MAXC 17      // max chunks per 64-row q-tile

// softmax computed in exp2 space: scale = (1/8) * log2(e)
#define QSCALE 0.18033688f

typedef _Float16 h16;
typedef _Float16 h16x8 __attribute__((ext_vector_type(8)));
typedef _Float16 h16x4 __attribute__((ext_vector_type(4)));
typedef float f32x4 __attribute__((ext_vector_type(4)));
typedef float f32x16 __attribute__((ext_vector_type(16)));

#define WF_ELEMS (12 * 32 * 64 * 8)         // 196608 h16, frag-packed W
#define QK_ELEMS (BATCH * SEQ * HDIM)       // 1048576 h16 each for Q/K/V frag
#define PB 262144                            // per-batch h16 in Q/K/V frag (128 tiles * 2048)
#define NSLOT (BATCH * BSLOT)

// valid-slot prefix: qt = 4a+b -> sum_{q<qt} (q/4+1) = (a+1)(2a+b)
__device__ __forceinline__ int slot_base(int qt) {
    int a = qt >> 2, b = qt & 3;
    return (a + 1) * (2 * a + b);
}

// k-slot permutation for MFMA A/B fragments: swap bits 2<->3 (self-inverse)
__device__ __forceinline__ int kperm(int u) {
    return (u & 3) | (((u >> 2) & 1) << 3) | (((u >> 3) & 1) << 2);
}

// compiler-proof async loads; completion via explicit counted vmcnt
template<int OFF>
__device__ __forceinline__ void gload_o(h16x8& dst, const h16* p) {
    asm volatile("global_load_dwordx4 %0, %1, off offset:%2" : "=v"(dst) : "v"(p), "n"(OFF));
}

// ---------------- prep: frag-pack W (f32->f16) and x (f32->f16) ----------------
__global__ __launch_bounds__(256) void prep(const float* __restrict__ Wq,
                                            const float* __restrict__ Wk,
                                            const float* __restrict__ Wv,
                                            const float* __restrict__ x,
                                            h16* __restrict__ Wf,
                                            h16* __restrict__ xh) {
    int b = blockIdx.x;
    if (b < 96) {
        int flat = b * 256 + threadIdx.x;     // (fg, kt, lane)
        int lane = flat & 63;
        int kt = (flat >> 6) & 31;
        int fg = flat >> 11;                  // 0..11
        int col = 16 * fg + (lane & 15);
        const float* W = (col < 64) ? Wq : (col < 128) ? Wk : Wv;
        int c = col & 63;
        int k0 = 32 * kt + 8 * (lane >> 4);
        h16x8 v;
        #pragma unroll
        for (int j = 0; j < 8; j++) v[j] = (h16)W[(size_t)(k0 + j) * 64 + c];
        *(h16x8*)(Wf + (size_t)flat * 8) = v;
        return;
    }
    size_t flat = (size_t)(b - 96) * 256 + threadIdx.x;   // (mt, kt, lane)
    int lane = (int)(flat & 63);
    int kt = (int)((flat >> 6) & 31);
    int mt = (int)(flat >> 11);               // 0..1023
    const float* xp = x + (size_t)(16 * mt + (lane & 15)) * DMODEL + 32 * kt + 8 * (lane >> 4);
    f32x4 lo = *(const f32x4*)xp;
    f32x4 hi = *(const f32x4*)(xp + 4);
    h16x8 v;
    #pragma unroll
    for (int j = 0; j < 4; j++) { v[j] = (h16)lo[j]; v[j + 4] = (h16)hi[j]; }
    *(h16x8*)(xh + flat * 8) = v;
}

// ---------------- QKV projection GEMM: frag-packed coalesced loads, quad-buffered ----------------
#define QISSUE(S, IMM)                                                        \
    gload_o<IMM>(a##S##0, ax0); gload_o<IMM>(a##S##1, ax1);                   \
    gload_o<IMM>(b##S##0, w0);  gload_o<IMM>(b##S##1, w1);                    \
    gload_o<IMM>(b##S##2, w2);

#define QCOMPUTE(S)                                                           \
    c00 = __builtin_amdgcn_mfma_f32_16x16x32_f16(a##S##0, b##S##0, c00, 0, 0, 0); \
    c01 = __builtin_amdgcn_mfma_f32_16x16x32_f16(a##S##0, b##S##1, c01, 0, 0, 0); \
    c02 = __builtin_amdgcn_mfma_f32_16x16x32_f16(a##S##0, b##S##2, c02, 0, 0, 0); \
    c10 = __builtin_amdgcn_mfma_f32_16x16x32_f16(a##S##1, b##S##0, c10, 0, 0, 0); \
    c11 = __builtin_amdgcn_mfma_f32_16x16x32_f16(a##S##1, b##S##1, c11, 0, 0, 0); \
    c12 = __builtin_amdgcn_mfma_f32_16x16x32_f16(a##S##1, b##S##2, c12, 0, 0, 0);

#define QSTEP(S, N) {                                                         \
    asm volatile("s_waitcnt vmcnt(" #N ")" ::: "memory");                     \
    __builtin_amdgcn_sched_barrier(0);                                        \
    QCOMPUTE(S)                                                               \
    QISSUE(S, 3072)                                                           \
    ax0 += 512; ax1 += 512; w0 += 512; w1 += 512; w2 += 512; }

#define QSTEP_T(S, N) {                                                       \
    asm volatile("s_waitcnt vmcnt(" #N ")" ::: "memory");                     \
    __builtin_amdgcn_sched_barrier(0);                                        \
    QCOMPUTE(S) }

__global__ __launch_bounds__(256, 2) void qkv_proj(
    const h16* __restrict__ xh, const h16* __restrict__ Wf,
    const float* __restrict__ bq, const float* __restrict__ bk, const float* __restrict__ bv,
    h16* __restrict__ Qf, h16* __restrict__ Kf, h16* __restrict__ Vf)
{
    int lane = threadIdx.x & 63;
    int w = threadIdx.x >> 6;
    int r0 = blockIdx.x * 32;
    int ln15 = lane & 15;

    // base pointers start at kt=1 (prologue offsets -1024..2048, steady +3072)
    const h16* ax0 = xh + (size_t)(2 * blockIdx.x) * 16384 + lane * 8 + 512;
    const h16* ax1 = ax0 + 16384;
    const h16* w0 = Wf + (size_t)(3 * w) * 16384 + lane * 8 + 512;
    const h16* w1 = w0 + 16384;
    const h16* w2 = w0 + 32768;

    h16x8 aA0, aA1, bA0, bA1, bA2;
    h16x8 aB0, aB1, bB0, bB1, bB2;
    h16x8 aC0, aC1, bC0, bC1, bC2;
    h16x8 aD0, aD1, bD0, bD1, bD2;
    f32x4 c00 = {}, c01 = {}, c02 = {}, c10 = {}, c11 = {}, c12 = {};

    QISSUE(A, -1024) QISSUE(B, 0) QISSUE(C, 1024) QISSUE(D, 2048)   // 20 in flight

    QSTEP(A, 15) QSTEP(B, 15) QSTEP(C, 15) QSTEP(D, 15)
    QSTEP(A, 15) QSTEP(B, 15) QSTEP(C, 15) QSTEP(D, 15)
    QSTEP(A, 15) QSTEP(B, 15) QSTEP(C, 15) QSTEP(D, 15)
    QSTEP(A, 15) QSTEP(B, 15) QSTEP(C, 15) QSTEP(D, 15)
    QSTEP(A, 15) QSTEP(B, 15) QSTEP(C, 15) QSTEP(D, 15)
    QSTEP(A, 15) QSTEP(B, 15) QSTEP(C, 15) QSTEP(D, 15)
    QSTEP(A, 15) QSTEP(B, 15) QSTEP(C, 15) QSTEP(D, 15)
    QSTEP_T(A, 15) QSTEP_T(B, 10) QSTEP_T(C, 5) QSTEP_T(D, 0)

    // epilogue: +bias, scatter-write into fragment-packed Q/K/V layouts
    f32x4 acc[2][3] = {{c00, c01, c02}, {c10, c11, c12}};
    #pragma unroll
    for (int f = 0; f < 3; f++) {
        int col = 48 * w + 16 * f + ln15;
        float bias = (col < 64) ? bq[col] : (col < 128) ? bk[col - 64] : bv[col - 128];
        #pragma unroll
        for (int m = 0; m < 2; m++) {
            #pragma unroll
            for (int i = 0; i < 4; i++) {
                int t = r0 + 16 * m + (lane >> 4) * 4 + i;
                int bb = t >> 12;
                int tt = t & (SEQ - 1);
                float v = acc[m][f][i] + bias;
                if (col < 64) {          // Q: frag[tq][d][hi*32+l31][e], exp2-space pre-scale
                    int d = col >> 4, hh = (col >> 3) & 1, e = col & 7;
                    Qf[(size_t)bb * PB + (tt >> 5) * 2048 + d * 512 +
                       (hh * 32 + (tt & 31)) * 8 + e] = (h16)(v * QSCALE);
                } else if (col < 128) {  // K
                    int ck = col - 64;
                    int d = ck >> 4, hh = (ck >> 3) & 1, e = ck & 7;
                    Kf[(size_t)bb * PB + (tt >> 5) * 2048 + d * 512 +
                       (hh * 32 + (tt & 31)) * 8 + e] = (h16)v;
                } else {                 // V: kperm folded into index
                    int h = col - 128;
                    int tp = (tt & ~15) | kperm(tt & 15);
                    int j = ((h >> 5) << 1) | ((tp >> 4) & 1);
                    Vf[(size_t)bb * PB + (tp >> 5) * 2048 + j * 512 +
                       (((tp >> 3) & 1) * 32 + (h & 31)) * 8 + (tp & 7)] = (h16)v;
                }
            }
        }
    }
}

// ---------------- flash compute step (one 32-row q-group): QK -> softmax -> PV ----------------
// exp2-space softmax (scale folded into Q); T13 defer-rescale.
__device__ __forceinline__ void flash_compute(
    h16x8 K0, h16x8 K1, h16x8 K2, h16x8 K3,
    h16x8 V0, h16x8 V1, h16x8 V2, h16x8 V3,
    h16x8 q0v, h16x8 q1v, h16x8 q2v, h16x8 q3v,
    int kt0, int q0g, int qg, int hi,
    f32x16& o0, f32x16& o1, float& m_i, float& l_i)
{
    f32x16 s = {};
    s = __builtin_amdgcn_mfma_f32_32x32x16_f16(K0, q0v, s, 0, 0, 0);
    s = __builtin_amdgcn_mfma_f32_32x32x16_f16(K1, q1v, s, 0, 0, 0);
    s = __builtin_amdgcn_mfma_f32_32x32x16_f16(K2, q2v, s, 0, 0, 0);
    s = __builtin_amdgcn_mfma_f32_32x32x16_f16(K3, q3v, s, 0, 0, 0);

    float sc[16];
    #pragma unroll
    for (int r = 0; r < 16; r++) sc[r] = s[r];
    if (kt0 + 31 > q0g) {
        #pragma unroll
        for (int r = 0; r < 16; r++) {
            int kg = kt0 + (r & 3) + 8 * (r >> 2) + 4 * hi;
            if (kg > qg) sc[r] = -1e30f;
        }
    }
    float tm = sc[0];
    #pragma unroll
    for (int r = 1; r < 16; r++) tm = fmaxf(tm, sc[r]);
    tm = fmaxf(tm, __shfl_xor(tm, 32));

    if (!__all(tm - m_i <= 8.f)) {       // rescale only when max actually grows
        float mn = fmaxf(m_i, tm);
        float al = exp2f(m_i - mn);
        m_i = mn;
        l_i *= al;
        #pragma unroll
        for (int r = 0; r < 16; r++) { o0[r] *= al; o1[r] *= al; }
    }

    float p[16], rs = 0.f;
    #pragma unroll
    for (int r = 0; r < 16; r++) { p[r] = exp2f(sc[r] - m_i); rs += p[r]; }
    rs += __shfl_xor(rs, 32);
    l_i += rs;

    h16x8 pb0, pb1;
    #pragma unroll
    for (int j = 0; j < 8; j++) { pb0[j] = (h16)p[j]; pb1[j] = (h16)p[8 + j]; }

    o0 = __builtin_amdgcn_mfma_f32_32x32x16_f16(V0, pb0, o0, 0, 0, 0);
    o0 = __builtin_amdgcn_mfma_f32_32x32x16_f16(V1, pb1, o0, 0, 0, 0);
    o1 = __builtin_amdgcn_mfma_f32_32x32x16_f16(V2, pb0, o1, 0, 0, 0);
    o1 = __builtin_amdgcn_mfma_f32_32x32x16_f16(V3, pb1, o1, 0, 0, 0);
}

// coalesced frag loads for one 32-kv tile (4 K + 4 V), then advance 4KB
#define ISSUE(B) {                                                            \
    gload_o<0>(k##B##0, kp);    gload_o<1024>(k##B##1, kp);                   \
    gload_o<2048>(k##B##2, kp); gload_o<3072>(k##B##3, kp);                   \
    gload_o<0>(v##B##0, vp);    gload_o<1024>(v##B##1, vp);                   \
    gload_o<2048>(v##B##2, vp); gload_o<3072>(v##B##3, vp);                   \
    kp += 2048; vp += 2048; }

#define COMPUTE(B, T) {                                                       \
    __builtin_amdgcn_s_setprio(1);                                            \
    flash_compute(k##B##0, k##B##1, k##B##2, k##B##3,                         \
                  v##B##0, v##B##1, v##B##2, v##B##3,                         \
                  qa0, qa1, qa2, qa3, S + 32 * (T), q0, qg0, hi,              \
                  o00, o01, m0, l0);                                          \
    flash_compute(k##B##0, k##B##1, k##B##2, k##B##3,                         \
                  v##B##0, v##B##1, v##B##2, v##B##3,                         \
                  qc0, qc1, qc2, qc3, S + 32 * (T), q0 + 32, qg1, hi,         \
                  o10, o11, m1, l1);                                          \
    __builtin_amdgcn_s_setprio(0); }

#define STEP(CUR, NXT, T) {                                                   \
    ISSUE(NXT)                                                                \
    asm volatile("s_waitcnt vmcnt(8)" ::: "memory");                          \
    __builtin_amdgcn_sched_barrier(0);                                        \
    COMPUTE(CUR, T) }

#define STEP_LAST(CUR, T) {                                                   \
    asm volatile("s_waitcnt vmcnt(0)" ::: "memory");                          \
    __builtin_amdgcn_sched_barrier(0);                                        \
    COMPUTE(CUR, T) }

// ---------------- causal flash attention partial: KV-locality block mapping ----------------
// Block = (batch, a, c): the 4 waves handle qt = 4a+wid, ALL at chunk c (c <= a).
// All four waves stream the IDENTICAL K/V chunk in near-lockstep -> CU L1 serves
// 3 of 4 waves; KV L2/L3 line traffic drops ~4x. Grid is exact (no idle waves),
// and every block runs the same 8-iteration loop (perfect balance).
__global__ __launch_bounds__(256, 2) void flash(
    const h16* __restrict__ Qf, const h16* __restrict__ Kf, const h16* __restrict__ Vf,
    h16* __restrict__ o_part, float* __restrict__ ml_part)
{
    int wid = threadIdx.x >> 6;
    int lane = threadIdx.x & 63;
    int bid = blockIdx.x;                  // grid = BATCH * 136
    int batch = bid / 136;
    int s = bid - batch * 136;
    int a = (int)((sqrtf(8.f * s + 1.f) - 1.f) * 0.5f);
    while ((a + 1) * (a + 2) / 2 <= s) a++;
    while (a * (a + 1) / 2 > s) a--;
    int c = s - a * (a + 1) / 2;           // chunk index, 0..a
    int qt = 4 * a + wid;                  // this wave's q-tile (nc = a+1)

    int q0 = qt * QBLK;
    int S = c * CHUNK;
    int l31 = lane & 31;
    int hi = lane >> 5;
    int qg0 = q0 + l31;
    int qg1 = q0 + 32 + l31;

    const h16* kp = Kf + (size_t)batch * PB + (S >> 5) * 2048 + lane * 8;
    const h16* vp = Vf + (size_t)batch * PB + (S >> 5) * 2048 + lane * 8;

    // Q fragments for both 32-row groups (coalesced; drained by first STEP's vmcnt(8))
    h16x8 qa0, qa1, qa2, qa3, qc0, qc1, qc2, qc3;
    {
        const h16* qp = Qf + (size_t)batch * PB + (q0 >> 5) * 2048 + lane * 8;
        gload_o<0>(qa0, qp); gload_o<1024>(qa1, qp);
        gload_o<2048>(qa2, qp); gload_o<3072>(qa3, qp);
        const h16* qp2 = qp + 2048;
        gload_o<0>(qc0, qp2); gload_o<1024>(qc1, qp2);
        gload_o<2048>(qc2, qp2); gload_o<3072>(qc3, qp2);
    }

    h16x8 kA0, kA1, kA2, kA3, vA0, vA1, vA2, vA3;
    h16x8 kB0, kB1, kB2, kB3, vB0, vB1, vB2, vB3;

    f32x16 o00 = {}, o01 = {}, o10 = {}, o11 = {};
    float m0 = -1e30f, l0 = 0.f, m1 = -1e30f, l1 = 0.f;

    ISSUE(A)               // prologue: 8 Q + 8 tile0 in flight

    STEP(A, B, 0)          // issue tile1 -> 24 out; vmcnt(8) = Q+tile0 done
    STEP(B, A, 1)
    STEP(A, B, 2)
    STEP(B, A, 3)
    STEP(A, B, 4)
    STEP(B, A, 5)
    STEP(A, B, 6)
    STEP_LAST(B, 7)

    // write l-normalized partials (f16) + (m, l) f32 for both groups
    size_t slot = (size_t)batch * BSLOT + slot_base(qt) + c;
    h16* opb = o_part + slot * (QBLK * 64);
    {
        float inv = 1.f / l0;
        h16* op = opb + l31 * 64;
        #pragma unroll
        for (int q = 0; q < 4; q++) {
            h16x4 pk0, pk1;
            #pragma unroll
            for (int i = 0; i < 4; i++) {
                pk0[i] = (h16)(o00[4 * q + i] * inv);
                pk1[i] = (h16)(o01[4 * q + i] * inv);
            }
            *(h16x4*)(op + 8 * q + 4 * hi) = pk0;
            *(h16x4*)(op + 32 + 8 * q + 4 * hi) = pk1;
        }
    }
    {
        float inv = 1.f / l1;
        h16* op = opb + (32 + l31) * 64;
        #pragma unroll
        for (int q = 0; q < 4; q++) {
            h16x4 pk0, pk1;
            #pragma unroll
            for (int i = 0; i < 4; i++) {
                pk0[i] = (h16)(o10[4 * q + i] * inv);
                pk1[i] = (h16)(o11[4 * q + i] * inv);
            }
            *(h16x4*)(op + 8 * q + 4 * hi) = pk0;
            *(h16x4*)(op + 32 + 8 * q + 4 * hi) = pk1;
        }
    }
    if (hi == 0) {
        ml_part[slot * 128 + l31 * 2] = m0;
        ml_part[slot * 128 + l31 * 2 + 1] = l0;
        ml_part[slot * 128 + (32 + l31) * 2] = m1;
        ml_part[slot * 128 + (32 + l31) * 2 + 1] = l1;
    }
}

// ---------------- combine partials: LDS ml, thread=(row, 4 cols), vectorized h16x4 ----------------
__global__ __launch_bounds__(256) void combine(
    const h16* __restrict__ o_part, const float* __restrict__ ml_part,
    float* __restrict__ out)
{
    __shared__ float mlds[MAXC * 128];
    int bid = blockIdx.x;           // BATCH*NQT*4
    int rq = bid & 3;               // 16-row quarter
    int tile = bid >> 2;
    int batch = tile >> 6;
    int qt = tile & (NQT - 1);
    int q0 = qt * QBLK;
    int nc = (qt >> 2) + 1;
    size_t base = (size_t)batch * BSLOT + slot_base(qt);

    // stage the ml slab (nc x 128 floats) coalesced into LDS
    for (int i = threadIdx.x; i < nc * 128; i += 256)
        mlds[i] = ml_part[base * 128 + i];
    __syncthreads();

    int r = rq * 16 + (threadIdx.x >> 4);   // this thread's row
    int c4 = (threadIdx.x & 15) * 4;        // 4 consecutive head-cols

    float M = -1e30f;
    for (int c = 0; c < nc; c++) M = fmaxf(M, mlds[c * 128 + r * 2]);

    const h16* op = o_part + base * (QBLK * 64) + r * 64 + c4;
    float L = 0.f;
    f32x4 A = {};
    #pragma unroll 4
    for (int c = 0; c < nc; c++) {          // 8B vector load per chunk, 4-deep pipelined
        float wt = exp2f(mlds[c * 128 + r * 2] - M) * mlds[c * 128 + r * 2 + 1];
        L += wt;
        h16x4 v = *(const h16x4*)(op + (size_t)c * (QBLK * 64));
        A[0] += wt * (float)v[0];
        A[1] += wt * (float)v[1];
        A[2] += wt * (float)v[2];
        A[3] += wt * (float)v[3];
    }
    f32x4 o;
    float inv = 1.f / L;
    #pragma unroll
    for (int j = 0; j < 4; j++) o[j] = A[j] * inv;
    *(f32x4*)(out + ((size_t)batch * SEQ + q0 + r) * HDIM + c4) = o;
}

extern "C" void kernel_launch(void* const* d_in, const int* in_sizes, int n_in,
                              void* d_out, int out_size, void* d_ws, size_t ws_size,
                              hipStream_t stream) {
    const float* x  = (const float*)d_in[0];
    const float* Wq = (const float*)d_in[1];
    const float* bq = (const float*)d_in[2];
    const float* Wk = (const float*)d_in[3];
    const float* bk = (const float*)d_in[4];
    const float* Wv = (const float*)d_in[5];
    const float* bv = (const float*)d_in[6];
    float* out = (float*)d_out;

    h16* Wf = (h16*)d_ws;
    h16* Qf = Wf + WF_ELEMS;
    h16* Kf = Qf + QK_ELEMS;
    h16* Vf = Kf + QK_ELEMS;
    h16* xh = Vf + QK_ELEMS;             // 32 MB, dead after qkv_proj
    h16* o_part = xh;                    // aliases xh (flash phase)
    float* ml_part = (float*)(o_part + (size_t)NSLOT * QBLK * 64);
    // peak ws use ~= 38.4 MiB (proven in R7/R8)

    hipLaunchKernelGGL(prep, dim3(96 + 8192), dim3(256), 0, stream, Wq, Wk, Wv, x, Wf, xh);
    hipLaunchKernelGGL(qkv_proj, dim3(512), dim3(256), 0, stream,
                       xh, Wf, bq, bk, bv, Qf, Kf, Vf);
    hipLaunchKernelGGL(flash, dim3(BATCH * 136), dim3(256), 0, stream,
                       Qf, Kf, Vf, o_part, ml_part);
    hipLaunchKernelGGL(combine, dim3(BATCH * NQT * 4), dim3(256), 0, stream,
                       o_part, ml_part, out);
}

// Round 17
// 62.057 us; speedup vs baseline: 2.4815x; 1.1563x over previous
//
#include <hip/hip_runtime.h>

#define BATCH 4
#define SEQ 4096
#define DMODEL 1024
#define HDIM 64

#define QBLK 64      // q rows per wave (2 groups of 32)
#define NQT 64       // 64-row q-tiles per batch
#define CHUNK 256    // KV positions per wave
#define ITERS 8      // CHUNK / 32
#define BSLOT 544    // per-batch valid (qt,chunk) slots = sum_qt (qt/4 + 1)
#define MAXC 17      // max chunks per 64-row q-tile

// softmax computed in exp2 space: scale = (1/8) * log2(e)
#define QSCALE 0.18033688f

typedef _Float16 h16;
typedef _Float16 h16x8 __attribute__((ext_vector_type(8)));
typedef _Float16 h16x4 __attribute__((ext_vector_type(4)));
typedef float f32x4 __attribute__((ext_vector_type(4)));
typedef float f32x16 __attribute__((ext_vector_type(16)));

#define WF_ELEMS (12 * 32 * 64 * 8)         // 196608 h16, frag-packed W
#define QK_ELEMS (BATCH * SEQ * HDIM)       // 1048576 h16 each for Q/K/V frag
#define PB 262144                            // per-batch h16 in Q/K/V frag (128 tiles * 2048)
#define NSLOT (BATCH * BSLOT)

// valid-slot prefix: qt = 4a+b -> sum_{q<qt} (q/4+1) = (a+1)(2a+b)
__device__ __forceinline__ int slot_base(int qt) {
    int a = qt >> 2, b = qt & 3;
    return (a + 1) * (2 * a + b);
}

// k-slot permutation for MFMA A/B fragments: swap bits 2<->3 (self-inverse)
__device__ __forceinline__ int kperm(int u) {
    return (u & 3) | (((u >> 2) & 1) << 3) | (((u >> 3) & 1) << 2);
}

// compiler-proof async loads; completion via explicit counted vmcnt
template<int OFF>
__device__ __forceinline__ void gload_o(h16x8& dst, const h16* p) {
    asm volatile("global_load_dwordx4 %0, %1, off offset:%2" : "=v"(dst) : "v"(p), "n"(OFF));
}
template<int OFF>
__device__ __forceinline__ void gloadf_o(f32x4& dst, const float* p) {
    asm volatile("global_load_dwordx4 %0, %1, off offset:%2" : "=v"(dst) : "v"(p), "n"(OFF));
}

#define MFMA16(a, b, c) __builtin_amdgcn_mfma_f32_16x16x32_f16(a, b, c, 0, 0, 0)

// ---------------- prep: frag-pack W (f32->f16) only ----------------
// W_frag[fg(12)][kt(32)][lane][8]: lane=(kgrp*16+ln15) holds W[32kt+8kgrp+e][16fg+ln15]
__global__ __launch_bounds__(256) void prep_w(const float* __restrict__ Wq,
                                              const float* __restrict__ Wk,
                                              const float* __restrict__ Wv,
                                              h16* __restrict__ Wf) {
    int flat = blockIdx.x * 256 + threadIdx.x;   // (fg, kt, lane), 96 blocks
    int lane = flat & 63;
    int kt = (flat >> 6) & 31;
    int fg = flat >> 11;                  // 0..11
    int col = 16 * fg + (lane & 15);
    const float* W = (col < 64) ? Wq : (col < 128) ? Wk : Wv;
    int c = col & 63;
    int k0 = 32 * kt + 8 * (lane >> 4);
    h16x8 v;
    #pragma unroll
    for (int j = 0; j < 8; j++) v[j] = (h16)W[(size_t)(k0 + j) * 64 + c];
    *(h16x8*)(Wf + (size_t)flat * 8) = v;
}

// ---------------- fused QKV projection: x f32 staged+converted in LDS ----------------
// Block owns 32 rows. 16 stages x 64 cols: stage s covers k-steps 2s, 2s+1.
// LDS buf[2][2048 h16] = frag-packed [kt2][mt][lane][8]; thread t stages
// x[r0 + (t>>3)][64s + (t&7)*8 .. +7] -> converts -> one ds_write_b128.
// W frags via asm loads, double-buffered sets A/B. One barrier per stage.
// W k-step stride = 512 h16 = 1024 BYTES; each WISSUE covers 2 k-steps (advance 1024 h16).
#define XISSUE(R, S) { gloadf_o<(S) * 256>(R##a, xp); gloadf_o<(S) * 256 + 16>(R##b, xp); }

#define WISSUE(S) {                                                           \
    gload_o<0>(wr##S##0, w0); gload_o<1024>(wr##S##1, w0);                    \
    gload_o<0>(wr##S##2, w1); gload_o<1024>(wr##S##3, w1);                    \
    gload_o<0>(wr##S##4, w2); gload_o<1024>(wr##S##5, w2);                    \
    w0 += 1024; w1 += 1024; w2 += 1024; }

#define XWRITE(R, P) {                                                        \
    h16x8 v_;                                                                 \
    _Pragma("unroll")                                                         \
    for (int j_ = 0; j_ < 4; j_++) { v_[j_] = (h16)R##a[j_]; v_[4 + j_] = (h16)R##b[j_]; } \
    *(h16x8*)(&xbuf[P][wo]) = v_; }

#define QCOMP(S, P) {                                                         \
    h16x8 a00 = *(const h16x8*)(&xbuf[P][lane * 8]);                          \
    h16x8 a01 = *(const h16x8*)(&xbuf[P][512 + lane * 8]);                    \
    c00 = MFMA16(a00, wr##S##0, c00); c01 = MFMA16(a00, wr##S##2, c01);       \
    c02 = MFMA16(a00, wr##S##4, c02);                                         \
    c10 = MFMA16(a01, wr##S##0, c10); c11 = MFMA16(a01, wr##S##2, c11);       \
    c12 = MFMA16(a01, wr##S##4, c12);                                         \
    h16x8 a10 = *(const h16x8*)(&xbuf[P][1024 + lane * 8]);                   \
    h16x8 a11 = *(const h16x8*)(&xbuf[P][1536 + lane * 8]);                   \
    c00 = MFMA16(a10, wr##S##1, c00); c01 = MFMA16(a10, wr##S##3, c01);       \
    c02 = MFMA16(a10, wr##S##5, c02);                                         \
    c10 = MFMA16(a11, wr##S##1, c10); c11 = MFMA16(a11, wr##S##3, c11);       \
    c12 = MFMA16(a11, wr##S##5, c12); }

#define VM0 { asm volatile("s_waitcnt vmcnt(0)" ::: "memory");                \
              __builtin_amdgcn_sched_barrier(0); }

// even stage s: compute buf0/setA; write x[s+1](xB)->buf1; issue x[s+2]->xA, W[s+2]->A
#define STGE(s) { QCOMP(A, 0) VM0 XWRITE(xB, 1) XISSUE(xA, (s) + 2) WISSUE(A) __syncthreads(); }
// odd stage s: compute buf1/setB; write xA->buf0; issue xB, setB
#define STGO(s) { QCOMP(B, 1) VM0 XWRITE(xA, 0) XISSUE(xB, (s) + 2) WISSUE(B) __syncthreads(); }

__global__ __launch_bounds__(256, 2) void qkv_fused(
    const float* __restrict__ x, const h16* __restrict__ Wf,
    const float* __restrict__ bq, const float* __restrict__ bk, const float* __restrict__ bv,
    h16* __restrict__ Qf, h16* __restrict__ Kf, h16* __restrict__ Vf)
{
    __shared__ h16 xbuf[2][2048];            // 2 x 4KB frag-packed stages
    int t = threadIdx.x;
    int lane = t & 63;
    int w = t >> 6;
    int r0 = blockIdx.x * 32;
    int ln15 = lane & 15;

    // x staging: thread t -> row t>>3, col chunk (t&7)*8; all offsets imm (s*256B)
    const float* xp = x + (size_t)(r0 + (t >> 3)) * DMODEL + (t & 7) * 8;
    // LDS write offset (h16 units): [kt2][mt][kgrp*16+ln15][8]
    int wo = ((t & 7) >> 2) * 1024 + ((t >> 3) >> 4) * 512 +
             ((t & 3) * 16 + ((t >> 3) & 15)) * 8;
    // W bases per wave (frag-packed; advance 1024 h16 = 2 k-steps per WISSUE)
    const h16* w0 = Wf + (size_t)(3 * w) * 16384 + lane * 8;
    const h16* w1 = w0 + 16384;
    const h16* w2 = w0 + 32768;

    f32x4 xAa, xAb, xBa, xBb;
    h16x8 wrA0, wrA1, wrA2, wrA3, wrA4, wrA5;
    h16x8 wrB0, wrB1, wrB2, wrB3, wrB4, wrB5;
    f32x4 c00 = {}, c01 = {}, c02 = {}, c10 = {}, c11 = {}, c12 = {};

    XISSUE(xA, 0) WISSUE(A) XISSUE(xB, 1) WISSUE(B)   // 16 in flight
    asm volatile("s_waitcnt vmcnt(8)" ::: "memory");   // x0 + W0 retired (FIFO)
    __builtin_amdgcn_sched_barrier(0);
    XWRITE(xA, 0)
    __syncthreads();

    STGE(0)  STGO(1)  STGE(2)  STGO(3)
    STGE(4)  STGO(5)  STGE(6)  STGO(7)
    STGE(8)  STGO(9)  STGE(10) STGO(11)
    STGE(12) STGO(13)
    // stage 14 (even, no re-issue):
    { QCOMP(A, 0) VM0 XWRITE(xB, 1) __syncthreads(); }
    // stage 15 (odd, final):
    { QCOMP(B, 1) }

    // epilogue: +bias, scatter-write into fragment-packed Q/K/V layouts
    f32x4 acc[2][3] = {{c00, c01, c02}, {c10, c11, c12}};
    #pragma unroll
    for (int f = 0; f < 3; f++) {
        int col = 48 * w + 16 * f + ln15;
        float bias = (col < 64) ? bq[col] : (col < 128) ? bk[col - 64] : bv[col - 128];
        #pragma unroll
        for (int m = 0; m < 2; m++) {
            #pragma unroll
            for (int i = 0; i < 4; i++) {
                int tr = r0 + 16 * m + (lane >> 4) * 4 + i;
                int bb = tr >> 12;
                int tt = tr & (SEQ - 1);
                float v = acc[m][f][i] + bias;
                if (col < 64) {          // Q: exp2-space pre-scale
                    int d = col >> 4, hh = (col >> 3) & 1, e = col & 7;
                    Qf[(size_t)bb * PB + (tt >> 5) * 2048 + d * 512 +
                       (hh * 32 + (tt & 31)) * 8 + e] = (h16)(v * QSCALE);
                } else if (col < 128) {  // K
                    int ck = col - 64;
                    int d = ck >> 4, hh = (ck >> 3) & 1, e = ck & 7;
                    Kf[(size_t)bb * PB + (tt >> 5) * 2048 + d * 512 +
                       (hh * 32 + (tt & 31)) * 8 + e] = (h16)v;
                } else {                 // V: kperm folded into index
                    int h = col - 128;
                    int tp = (tt & ~15) | kperm(tt & 15);
                    int j = ((h >> 5) << 1) | ((tp >> 4) & 1);
                    Vf[(size_t)bb * PB + (tp >> 5) * 2048 + j * 512 +
                       (((tp >> 3) & 1) * 32 + (h & 31)) * 8 + (tp & 7)] = (h16)v;
                }
            }
        }
    }
}

// ---------------- flash compute step (one 32-row q-group): QK -> softmax -> PV ----------------
// exp2-space softmax (scale folded into Q); T13 defer-rescale.
__device__ __forceinline__ void flash_compute(
    h16x8 K0, h16x8 K1, h16x8 K2, h16x8 K3,
    h16x8 V0, h16x8 V1, h16x8 V2, h16x8 V3,
    h16x8 q0v, h16x8 q1v, h16x8 q2v, h16x8 q3v,
    int kt0, int q0g, int qg, int hi,
    f32x16& o0, f32x16& o1, float& m_i, float& l_i)
{
    f32x16 s = {};
    s = __builtin_amdgcn_mfma_f32_32x32x16_f16(K0, q0v, s, 0, 0, 0);
    s = __builtin_amdgcn_mfma_f32_32x32x16_f16(K1, q1v, s, 0, 0, 0);
    s = __builtin_amdgcn_mfma_f32_32x32x16_f16(K2, q2v, s, 0, 0, 0);
    s = __builtin_amdgcn_mfma_f32_32x32x16_f16(K3, q3v, s, 0, 0, 0);

    float sc[16];
    #pragma unroll
    for (int r = 0; r < 16; r++) sc[r] = s[r];
    if (kt0 + 31 > q0g) {
        #pragma unroll
        for (int r = 0; r < 16; r++) {
            int kg = kt0 + (r & 3) + 8 * (r >> 2) + 4 * hi;
            if (kg > qg) sc[r] = -1e30f;
        }
    }
    float tm = sc[0];
    #pragma unroll
    for (int r = 1; r < 16; r++) tm = fmaxf(tm, sc[r]);
    tm = fmaxf(tm, __shfl_xor(tm, 32));

    if (!__all(tm - m_i <= 8.f)) {       // rescale only when max actually grows
        float mn = fmaxf(m_i, tm);
        float al = exp2f(m_i - mn);
        m_i = mn;
        l_i *= al;
        #pragma unroll
        for (int r = 0; r < 16; r++) { o0[r] *= al; o1[r] *= al; }
    }

    float p[16], rs = 0.f;
    #pragma unroll
    for (int r = 0; r < 16; r++) { p[r] = exp2f(sc[r] - m_i); rs += p[r]; }
    rs += __shfl_xor(rs, 32);
    l_i += rs;

    h16x8 pb0, pb1;
    #pragma unroll
    for (int j = 0; j < 8; j++) { pb0[j] = (h16)p[j]; pb1[j] = (h16)p[8 + j]; }

    o0 = __builtin_amdgcn_mfma_f32_32x32x16_f16(V0, pb0, o0, 0, 0, 0);
    o0 = __builtin_amdgcn_mfma_f32_32x32x16_f16(V1, pb1, o0, 0, 0, 0);
    o1 = __builtin_amdgcn_mfma_f32_32x32x16_f16(V2, pb0, o1, 0, 0, 0);
    o1 = __builtin_amdgcn_mfma_f32_32x32x16_f16(V3, pb1, o1, 0, 0, 0);
}

// coalesced frag loads for one 32-kv tile (4 K + 4 V), then advance 4KB
#define ISSUE(B) {                                                            \
    gload_o<0>(k##B##0, kp);    gload_o<1024>(k##B##1, kp);                   \
    gload_o<2048>(k##B##2, kp); gload_o<3072>(k##B##3, kp);                   \
    gload_o<0>(v##B##0, vp);    gload_o<1024>(v##B##1, vp);                   \
    gload_o<2048>(v##B##2, vp); gload_o<3072>(v##B##3, vp);                   \
    kp += 2048; vp += 2048; }

#define COMPUTE(B, T) {                                                       \
    __builtin_amdgcn_s_setprio(1);                                            \
    flash_compute(k##B##0, k##B##1, k##B##2, k##B##3,                         \
                  v##B##0, v##B##1, v##B##2, v##B##3,                         \
                  qa0, qa1, qa2, qa3, S + 32 * (T), q0, qg0, hi,              \
                  o00, o01, m0, l0);                                          \
    flash_compute(k##B##0, k##B##1, k##B##2, k##B##3,                         \
                  v##B##0, v##B##1, v##B##2, v##B##3,                         \
                  qc0, qc1, qc2, qc3, S + 32 * (T), q0 + 32, qg1, hi,         \
                  o10, o11, m1, l1);                                          \
    __builtin_amdgcn_s_setprio(0); }

#define STEP(CUR, NXT, T) {                                                   \
    ISSUE(NXT)                                                                \
    asm volatile("s_waitcnt vmcnt(8)" ::: "memory");                          \
    __builtin_amdgcn_sched_barrier(0);                                        \
    COMPUTE(CUR, T) }

#define STEP_LAST(CUR, T) {                                                   \
    asm volatile("s_waitcnt vmcnt(0)" ::: "memory");                          \
    __builtin_amdgcn_sched_barrier(0);                                        \
    COMPUTE(CUR, T) }

// ---------------- causal flash attention partial: KV-locality block mapping ----------------
// Block = (batch, a, c): the 4 waves handle qt = 4a+wid, ALL at chunk c (c <= a).
__global__ __launch_bounds__(256, 2) void flash(
    const h16* __restrict__ Qf, const h16* __restrict__ Kf, const h16* __restrict__ Vf,
    h16* __restrict__ o_part, float* __restrict__ ml_part)
{
    int wid = threadIdx.x >> 6;
    int lane = threadIdx.x & 63;
    int bid = blockIdx.x;                  // grid = BATCH * 136
    int batch = bid / 136;
    int s = bid - batch * 136;
    int a = (int)((sqrtf(8.f * s + 1.f) - 1.f) * 0.5f);
    while ((a + 1) * (a + 2) / 2 <= s) a++;
    while (a * (a + 1) / 2 > s) a--;
    int c = s - a * (a + 1) / 2;           // chunk index, 0..a
    int qt = 4 * a + wid;                  // this wave's q-tile (nc = a+1)

    int q0 = qt * QBLK;
    int S = c * CHUNK;
    int l31 = lane & 31;
    int hi = lane >> 5;
    int qg0 = q0 + l31;
    int qg1 = q0 + 32 + l31;

    const h16* kp = Kf + (size_t)batch * PB + (S >> 5) * 2048 + lane * 8;
    const h16* vp = Vf + (size_t)batch * PB + (S >> 5) * 2048 + lane * 8;

    h16x8 qa0, qa1, qa2, qa3, qc0, qc1, qc2, qc3;
    {
        const h16* qp = Qf + (size_t)batch * PB + (q0 >> 5) * 2048 + lane * 8;
        gload_o<0>(qa0, qp); gload_o<1024>(qa1, qp);
        gload_o<2048>(qa2, qp); gload_o<3072>(qa3, qp);
        const h16* qp2 = qp + 2048;
        gload_o<0>(qc0, qp2); gload_o<1024>(qc1, qp2);
        gload_o<2048>(qc2, qp2); gload_o<3072>(qc3, qp2);
    }

    h16x8 kA0, kA1, kA2, kA3, vA0, vA1, vA2, vA3;
    h16x8 kB0, kB1, kB2, kB3, vB0, vB1, vB2, vB3;

    f32x16 o00 = {}, o01 = {}, o10 = {}, o11 = {};
    float m0 = -1e30f, l0 = 0.f, m1 = -1e30f, l1 = 0.f;

    ISSUE(A)               // prologue: 8 Q + 8 tile0 in flight

    STEP(A, B, 0)
    STEP(B, A, 1)
    STEP(A, B, 2)
    STEP(B, A, 3)
    STEP(A, B, 4)
    STEP(B, A, 5)
    STEP(A, B, 6)
    STEP_LAST(B, 7)

    size_t slot = (size_t)batch * BSLOT + slot_base(qt) + c;
    h16* opb = o_part + slot * (QBLK * 64);
    {
        float inv = 1.f / l0;
        h16* op = opb + l31 * 64;
        #pragma unroll
        for (int q = 0; q < 4; q++) {
            h16x4 pk0, pk1;
            #pragma unroll
            for (int i = 0; i < 4; i++) {
                pk0[i] = (h16)(o00[4 * q + i] * inv);
                pk1[i] = (h16)(o01[4 * q + i] * inv);
            }
            *(h16x4*)(op + 8 * q + 4 * hi) = pk0;
            *(h16x4*)(op + 32 + 8 * q + 4 * hi) = pk1;
        }
    }
    {
        float inv = 1.f / l1;
        h16* op = opb + (32 + l31) * 64;
        #pragma unroll
        for (int q = 0; q < 4; q++) {
            h16x4 pk0, pk1;
            #pragma unroll
            for (int i = 0; i < 4; i++) {
                pk0[i] = (h16)(o10[4 * q + i] * inv);
                pk1[i] = (h16)(o11[4 * q + i] * inv);
            }
            *(h16x4*)(op + 8 * q + 4 * hi) = pk0;
            *(h16x4*)(op + 32 + 8 * q + 4 * hi) = pk1;
        }
    }
    if (hi == 0) {
        ml_part[slot * 128 + l31 * 2] = m0;
        ml_part[slot * 128 + l31 * 2 + 1] = l0;
        ml_part[slot * 128 + (32 + l31) * 2] = m1;
        ml_part[slot * 128 + (32 + l31) * 2 + 1] = l1;
    }
}

// ---------------- combine partials: LDS ml, thread=(row, 4 cols), vectorized h16x4 ----------------
__global__ __launch_bounds__(256) void combine(
    const h16* __restrict__ o_part, const float* __restrict__ ml_part,
    float* __restrict__ out)
{
    __shared__ float mlds[MAXC * 128];
    int bid = blockIdx.x;           // BATCH*NQT*4
    int rq = bid & 3;               // 16-row quarter
    int tile = bid >> 2;
    int batch = tile >> 6;
    int qt = tile & (NQT - 1);
    int q0 = qt * QBLK;
    int nc = (qt >> 2) + 1;
    size_t base = (size_t)batch * BSLOT + slot_base(qt);

    for (int i = threadIdx.x; i < nc * 128; i += 256)
        mlds[i] = ml_part[base * 128 + i];
    __syncthreads();

    int r = rq * 16 + (threadIdx.x >> 4);   // this thread's row
    int c4 = (threadIdx.x & 15) * 4;        // 4 consecutive head-cols

    float M = -1e30f;
    for (int c = 0; c < nc; c++) M = fmaxf(M, mlds[c * 128 + r * 2]);

    const h16* op = o_part + base * (QBLK * 64) + r * 64 + c4;
    float L = 0.f;
    f32x4 A = {};
    #pragma unroll 4
    for (int c = 0; c < nc; c++) {
        float wt = exp2f(mlds[c * 128 + r * 2] - M) * mlds[c * 128 + r * 2 + 1];
        L += wt;
        h16x4 v = *(const h16x4*)(op + (size_t)c * (QBLK * 64));
        A[0] += wt * (float)v[0];
        A[1] += wt * (float)v[1];
        A[2] += wt * (float)v[2];
        A[3] += wt * (float)v[3];
    }
    f32x4 o;
    float inv = 1.f / L;
    #pragma unroll
    for (int j = 0; j < 4; j++) o[j] = A[j] * inv;
    *(f32x4*)(out + ((size_t)batch * SEQ + q0 + r) * HDIM + c4) = o;
}

extern "C" void kernel_launch(void* const* d_in, const int* in_sizes, int n_in,
                              void* d_out, int out_size, void* d_ws, size_t ws_size,
                              hipStream_t stream) {
    const float* x  = (const float*)d_in[0];
    const float* Wq = (const float*)d_in[1];
    const float* bq = (const float*)d_in[2];
    const float* Wk = (const float*)d_in[3];
    const float* bk = (const float*)d_in[4];
    const float* Wv = (const float*)d_in[5];
    const float* bv = (const float*)d_in[6];
    float* out = (float*)d_out;

    h16* Wf = (h16*)d_ws;
    h16* Qf = Wf + WF_ELEMS;
    h16* Kf = Qf + QK_ELEMS;
    h16* Vf = Kf + QK_ELEMS;
    h16* o_part = Vf + QK_ELEMS;
    float* ml_part = (float*)(o_part + (size_t)NSLOT * QBLK * 64);
    // peak ws use ~= 25.3 MiB

    hipLaunchKernelGGL(prep_w, dim3(96), dim3(256), 0, stream, Wq, Wk, Wv, Wf);
    hipLaunchKernelGGL(qkv_fused, dim3(512), dim3(256), 0, stream,
                       x, Wf, bq, bk, bv, Qf, Kf, Vf);
    hipLaunchKernelGGL(flash, dim3(BATCH * 136), dim3(256), 0, stream,
                       Qf, Kf, Vf, o_part, ml_part);
    hipLaunchKernelGGL(combine, dim3(BATCH * NQT * 4), dim3(256), 0, stream,
                       o_part, ml_part, out);
}